// Round 1
// baseline (515.780 us; speedup 1.0000x reference)
//
#include <hip/hip_runtime.h>

// CQAttention fused pipeline for MI355X (gfx950).
// B=32, D=256, Lc=2048, Lq=256, fp32 in/out, bf16 MFMA internally.
// Workspace use: ~75 MB (S fp32 64MiB + stats + Qtb/Utb bf16).

#define B_ 32
#define D_ 256
#define LC 2048
#define LQ 256
#define NEG_INF (-1e30f)

using bf16   = __bf16;
using bf16x4 = __attribute__((ext_vector_type(4))) __bf16;
using bf16x8 = __attribute__((ext_vector_type(8))) __bf16;
using f32x4  = __attribute__((ext_vector_type(4))) float;

static __device__ __forceinline__ f32x4 mfma16(bf16x8 a, bf16x8 b, f32x4 c) {
  return __builtin_amdgcn_mfma_f32_16x16x32_bf16(a, b, c, 0, 0, 0);
}

// ---------------------------------------------------------------------------
// K0a: transpose Q (b,d,q) f32 -> Qtb (b,q,d) bf16
// ---------------------------------------------------------------------------
__global__ __launch_bounds__(256) void qprep(const float* __restrict__ Q,
                                             bf16* __restrict__ Qtb) {
  __shared__ float t[64][65];
  const int b  = blockIdx.y;
  const int qt = (blockIdx.x >> 2) * 64;
  const int dt = (blockIdx.x & 3) * 64;
  const int c  = threadIdx.x & 63, r0 = threadIdx.x >> 6;
  const float* Qb = Q + (size_t)b * D_ * LQ;
#pragma unroll
  for (int r = r0; r < 64; r += 4) t[r][c] = Qb[(size_t)(dt + r) * LQ + qt + c];
  __syncthreads();
  bf16* O = Qtb + (size_t)b * LQ * D_;
#pragma unroll
  for (int r = r0; r < 64; r += 4)
    O[(size_t)(qt + r) * D_ + dt + c] = (bf16)t[c][r];  // Qtb[q][d] = Q[d][q]
}

// ---------------------------------------------------------------------------
// K0b: bq[b][q] = sum_d Q[b,d,q] * w2[d]
// ---------------------------------------------------------------------------
__global__ __launch_bounds__(256) void bqkern(const float* __restrict__ Q,
                                              const float* __restrict__ w,
                                              float* __restrict__ bq) {
  const int b = blockIdx.x, q = threadIdx.x;
  const float* Qb = Q + (size_t)b * D_ * LQ;
  float acc = 0.f;
  for (int d = 0; d < D_; ++d) acc += Qb[(size_t)d * LQ + q] * w[D_ + d];
  bq[b * LQ + q] = acc;
}

// ---------------------------------------------------------------------------
// K1: S = (C*w3)^T @ Q + a[c] + bq[q]  (raw S), plus row softmax stats
//     (qmask logits) and per-tile column partial stats (cmask logits).
// Tile: BM=64 (c) x BN=256 (q, full) x K=256 (d), BK=64. 4 waves, n-split.
// ---------------------------------------------------------------------------
__global__ __launch_bounds__(256) void k1_sgemm(
    const float* __restrict__ C, const bf16* __restrict__ Qtb,
    const float* __restrict__ w, const float* __restrict__ cmask,
    const float* __restrict__ qmask, const float* __restrict__ bq,
    float* __restrict__ S, float* __restrict__ rmaxg, float* __restrict__ rsumg,
    float* __restrict__ cpmax, float* __restrict__ cpsum) {
  __shared__ __align__(16) bf16 As[64][72];
  __shared__ __align__(16) bf16 Bs[256][72];
  __shared__ float ared[4][64];
  __shared__ float wred[4][64];
  __shared__ float wsum[4][64];
  __shared__ float cml[64];
  __shared__ float qml[256];
  __shared__ float bql[256];

  const int b = blockIdx.y, ct = blockIdx.x, c0 = ct * 64;
  const int tid = threadIdx.x, lane = tid & 63, wv = tid >> 6;
  const float* Cb = C + (size_t)b * D_ * LC;
  const bf16* Qt = Qtb + (size_t)b * LQ * D_;
  const float* w1 = w;
  const float* w3 = w + 2 * D_;

  if (tid < 64) cml[tid] = cmask[b * LC + c0 + tid];
  qml[tid] = qmask[b * LQ + tid];
  bql[tid] = bq[b * LQ + tid];

  f32x4 acc[4][4];
#pragma unroll
  for (int i = 0; i < 4; i++)
#pragma unroll
    for (int j = 0; j < 4; j++) acc[i][j] = {0.f, 0.f, 0.f, 0.f};
  float acc_a = 0.f;

  const int sm = tid & 63;   // staging: m (c)
  const int skg = tid >> 6;  // staging: k-group

  for (int k0 = 0; k0 < D_; k0 += 64) {
    // A-tile: As[m][k] = C[b][k0+k][c0+m] * w3 ; fold a-bias accumulation.
#pragma unroll
    for (int i = 0; i < 16; ++i) {
      const int k = skg * 16 + i, kg = k0 + k;
      const float v = Cb[(size_t)kg * LC + c0 + sm];
      As[sm][k] = (bf16)(v * w3[kg]);
      acc_a += v * w1[kg];
    }
    // B-tile: Bs[q][k] = Qtb[b][q][k0+k]  (256 x 64 bf16)
#pragma unroll
    for (int p = 0; p < 8; ++p) {
      const int idx = (p * 256 + tid) * 8;
      const int q = idx >> 6, kk = idx & 63;
      *(bf16x8*)(&Bs[q][kk]) = *(const bf16x8*)(Qt + (size_t)q * D_ + k0 + kk);
    }
    __syncthreads();
#pragma unroll
    for (int kk = 0; kk < 64; kk += 32) {
      bf16x8 af[4], bfr[4];
#pragma unroll
      for (int mi = 0; mi < 4; mi++)
        af[mi] = *(const bf16x8*)(&As[mi * 16 + (lane & 15)][kk + (lane >> 4) * 8]);
#pragma unroll
      for (int ni = 0; ni < 4; ni++)
        bfr[ni] = *(const bf16x8*)(&Bs[wv * 64 + ni * 16 + (lane & 15)][kk + (lane >> 4) * 8]);
#pragma unroll
      for (int mi = 0; mi < 4; mi++)
#pragma unroll
        for (int ni = 0; ni < 4; ni++)
          acc[mi][ni] = mfma16(af[mi], bfr[ni], acc[mi][ni]);
    }
    __syncthreads();
  }

  ared[skg][sm] = acc_a;
  __syncthreads();

  const int r4 = (lane >> 4) * 4;  // fragment row base
  const int cn = lane & 15;        // fragment col

  // acc <- raw S = gemm + a[c] + bq[q]
#pragma unroll
  for (int mi = 0; mi < 4; mi++)
#pragma unroll
    for (int j = 0; j < 4; j++) {
      const int m = mi * 16 + r4 + j;
      const float aval = ared[0][m] + ared[1][m] + ared[2][m] + ared[3][m];
#pragma unroll
      for (int ni = 0; ni < 4; ni++) {
        const int n = wv * 64 + ni * 16 + cn;
        acc[mi][ni][j] += aval + bql[n];
      }
    }

  // store raw S
  float* Sb = S + ((size_t)b * LC + c0) * LQ;
#pragma unroll
  for (int mi = 0; mi < 4; mi++)
#pragma unroll
    for (int j = 0; j < 4; j++) {
      const int m = mi * 16 + r4 + j;
#pragma unroll
      for (int ni = 0; ni < 4; ni++) {
        const int n = wv * 64 + ni * 16 + cn;
        Sb[(size_t)m * LQ + n] = acc[mi][ni][j];
      }
    }

  // ---- row stats (softmax over q, qmask logits) ----
  float gmx[4][4];
#pragma unroll
  for (int mi = 0; mi < 4; mi++)
#pragma unroll
    for (int j = 0; j < 4; j++) {
      float mx = -3.0e38f;
#pragma unroll
      for (int ni = 0; ni < 4; ni++) {
        const int n = wv * 64 + ni * 16 + cn;
        const float qm = qml[n];
        const float lg = acc[mi][ni][j] * qm + (1.f - qm) * NEG_INF;
        mx = fmaxf(mx, lg);
      }
      for (int s = 1; s < 16; s <<= 1) mx = fmaxf(mx, __shfl_xor(mx, s));
      if (cn == 0) wred[wv][mi * 16 + r4 + j] = mx;
    }
  __syncthreads();
#pragma unroll
  for (int mi = 0; mi < 4; mi++)
#pragma unroll
    for (int j = 0; j < 4; j++) {
      const int m = mi * 16 + r4 + j;
      gmx[mi][j] = fmaxf(fmaxf(wred[0][m], wred[1][m]), fmaxf(wred[2][m], wred[3][m]));
      float ps = 0.f;
#pragma unroll
      for (int ni = 0; ni < 4; ni++) {
        const int n = wv * 64 + ni * 16 + cn;
        const float qm = qml[n];
        const float lg = acc[mi][ni][j] * qm + (1.f - qm) * NEG_INF;
        ps += __expf(lg - gmx[mi][j]);
      }
      for (int s = 1; s < 16; s <<= 1) ps += __shfl_xor(ps, s);
      if (cn == 0) wsum[wv][m] = ps;
    }
  __syncthreads();
  if (tid < 64) {
    const int m = tid;
    const float rm = fmaxf(fmaxf(wred[0][m], wred[1][m]), fmaxf(wred[2][m], wred[3][m]));
    const float rs = wsum[0][m] + wsum[1][m] + wsum[2][m] + wsum[3][m];
    rmaxg[b * LC + c0 + m] = rm;
    rsumg[b * LC + c0 + m] = rs;
  }

  // ---- column partial stats over this 64-row tile (cmask logits) ----
#pragma unroll
  for (int ni = 0; ni < 4; ni++) {
    const int n = wv * 64 + ni * 16 + cn;
    float mx = -3.0e38f;
#pragma unroll
    for (int mi = 0; mi < 4; mi++)
#pragma unroll
      for (int j = 0; j < 4; j++) {
        const int m = mi * 16 + r4 + j;
        const float cmv = cml[m];
        const float lg = acc[mi][ni][j] * cmv + (1.f - cmv) * NEG_INF;
        mx = fmaxf(mx, lg);
      }
    mx = fmaxf(mx, __shfl_xor(mx, 16));
    mx = fmaxf(mx, __shfl_xor(mx, 32));
    float ps = 0.f;
#pragma unroll
    for (int mi = 0; mi < 4; mi++)
#pragma unroll
      for (int j = 0; j < 4; j++) {
        const int m = mi * 16 + r4 + j;
        const float cmv = cml[m];
        const float lg = acc[mi][ni][j] * cmv + (1.f - cmv) * NEG_INF;
        ps += __expf(lg - mx);
      }
    ps += __shfl_xor(ps, 16);
    ps += __shfl_xor(ps, 32);
    if ((lane >> 4) == 0) {
      cpmax[((size_t)(b * 32 + ct)) * LQ + n] = mx;
      cpsum[((size_t)(b * 32 + ct)) * LQ + n] = ps;
    }
  }
}

// ---------------------------------------------------------------------------
// K2: combine 32 column-partial stats -> cmax/csum per (b,q). Exact merge.
// ---------------------------------------------------------------------------
__global__ __launch_bounds__(256) void k2_colstats(const float* __restrict__ cpmax,
                                                   const float* __restrict__ cpsum,
                                                   float* __restrict__ cmaxg,
                                                   float* __restrict__ csumg) {
  const int b = blockIdx.x, q = threadIdx.x;
  float m = -3.0e38f;
  for (int t = 0; t < 32; t++) m = fmaxf(m, cpmax[(size_t)(b * 32 + t) * LQ + q]);
  float s = 0.f;
  for (int t = 0; t < 32; t++)
    s += cpsum[(size_t)(b * 32 + t) * LQ + q] * __expf(cpmax[(size_t)(b * 32 + t) * LQ + q] - m);
  cmaxg[b * LQ + q] = m;
  csumg[b * LQ + q] = s;
}

// ---------------------------------------------------------------------------
// K3: U[q,d] = sum_c S2[c,q] * Ct[c,d]; store transposed Utb[b][d][q] bf16.
// Tile: 128(q) x 128(d), K=2048 over c in BK=64 steps. 4 waves (2x2).
// ---------------------------------------------------------------------------
__global__ __launch_bounds__(256) void k3_ugemm(
    const float* __restrict__ S, const float* __restrict__ C,
    const float* __restrict__ cmask, const float* __restrict__ cmaxg,
    const float* __restrict__ csumg, bf16* __restrict__ Utb) {
  __shared__ __align__(16) bf16 As[128][72];
  __shared__ __align__(16) bf16 Bs[128][72];
  const int b = blockIdx.y;
  const int mt = (blockIdx.x >> 1) * 128;  // q offset
  const int nt = (blockIdx.x & 1) * 128;   // d offset
  const int tid = threadIdx.x, lane = tid & 63, wv = tid >> 6;
  const int wm = (wv >> 1) * 64, wn = (wv & 1) * 64;

  const float* Sb = S + (size_t)b * LC * LQ;
  const float* Cb = C + (size_t)b * D_ * LC;

  const int am = tid & 127, akh = tid >> 7;  // A staging: m (q), k-half
  const float cmx = cmaxg[b * LQ + mt + am];
  const float csv = 1.0f / csumg[b * LQ + mt + am];

  f32x4 acc[4][4];
#pragma unroll
  for (int i = 0; i < 4; i++)
#pragma unroll
    for (int j = 0; j < 4; j++) acc[i][j] = {0.f, 0.f, 0.f, 0.f};

  for (int k0 = 0; k0 < LC; k0 += 64) {
    // A: As[m][k] = S2[c=k0+k][q=mt+m]
#pragma unroll
    for (int i = 0; i < 32; ++i) {
      const int k = akh * 32 + i, c = k0 + k;
      const float cmv = cmask[b * LC + c];
      const float sv = Sb[(size_t)c * LQ + mt + am];
      const float lg = sv * cmv + (1.f - cmv) * NEG_INF;
      As[am][k] = (bf16)(__expf(lg - cmx) * csv);
    }
    // B: Bs[n][k] = Ct[c=k0+k][d=nt+n] = C[b][nt+n][k0+k]
#pragma unroll
    for (int p = 0; p < 8; ++p) {
      const int idx = p * 256 + tid;
      const int n = idx >> 4, kq = (idx & 15) * 4;
      const f32x4 v = *(const f32x4*)(Cb + (size_t)(nt + n) * LC + k0 + kq);
      bf16x4 o = {(bf16)v[0], (bf16)v[1], (bf16)v[2], (bf16)v[3]};
      *(bf16x4*)(&Bs[n][kq]) = o;
    }
    __syncthreads();
#pragma unroll
    for (int kk = 0; kk < 64; kk += 32) {
      bf16x8 af[4], bfr[4];
#pragma unroll
      for (int mi = 0; mi < 4; mi++)
        af[mi] = *(const bf16x8*)(&As[wm + mi * 16 + (lane & 15)][kk + (lane >> 4) * 8]);
#pragma unroll
      for (int ni = 0; ni < 4; ni++)
        bfr[ni] = *(const bf16x8*)(&Bs[wn + ni * 16 + (lane & 15)][kk + (lane >> 4) * 8]);
#pragma unroll
      for (int mi = 0; mi < 4; mi++)
#pragma unroll
        for (int ni = 0; ni < 4; ni++)
          acc[mi][ni] = mfma16(af[mi], bfr[ni], acc[mi][ni]);
    }
    __syncthreads();
  }

  // store Utb[b][d][q] (4 consecutive q per lane)
  bf16* Ub = Utb + (size_t)b * D_ * LQ;
#pragma unroll
  for (int mi = 0; mi < 4; mi++)
#pragma unroll
    for (int ni = 0; ni < 4; ni++) {
      const int q = mt + wm + mi * 16 + (lane >> 4) * 4;
      const int d = nt + wn + ni * 16 + (lane & 15);
      bf16x4 o = {(bf16)acc[mi][ni][0], (bf16)acc[mi][ni][1],
                  (bf16)acc[mi][ni][2], (bf16)acc[mi][ni][3]};
      *(bf16x4*)(Ub + (size_t)d * LQ + q) = o;
    }
}

// ---------------------------------------------------------------------------
// K4: A = S1 @ Qt, Bv = S1 @ U (shared S1 tiles); emit all 4 output sections.
// Tile: BM=64 (c) x BN=128 (d), K=256 (q), BK=64. Waves 2x2 (32x64 each).
// ---------------------------------------------------------------------------
__global__ __launch_bounds__(256) void k4_final(
    const float* __restrict__ S, const float* __restrict__ C,
    const float* __restrict__ Q, const bf16* __restrict__ Utb,
    const float* __restrict__ qmask, const float* __restrict__ rmaxg,
    const float* __restrict__ rsumg, float* __restrict__ out) {
  union __align__(16) Sm {
    struct {
      bf16 As[64][72];
      bf16 B1[128][72];
      bf16 B2[128][72];
    } st;
    float bounce[64][129];
  };
  __shared__ Sm sm;
  __shared__ float rml[64], rsl[64], qml[256];

  const int b = blockIdx.y;
  const int ct = blockIdx.x >> 1, c0 = ct * 64;
  const int nt = (blockIdx.x & 1) * 128;
  const int tid = threadIdx.x, lane = tid & 63, wv = tid >> 6;
  const int wm = (wv >> 1) * 32, wn = (wv & 1) * 64;

  if (tid < 64) {
    rml[tid] = rmaxg[b * LC + c0 + tid];
    rsl[tid] = 1.0f / rsumg[b * LC + c0 + tid];
  }
  qml[tid] = qmask[b * LQ + tid];
  __syncthreads();

  const float* Sb = S + ((size_t)b * LC + c0) * LQ;
  const float* Cb = C + (size_t)b * D_ * LC;
  const float* Qb = Q + (size_t)b * D_ * LQ;
  const bf16* Ub = Utb + (size_t)b * D_ * LQ;

  f32x4 acc1[2][4], acc2[2][4];
#pragma unroll
  for (int i = 0; i < 2; i++)
#pragma unroll
    for (int j = 0; j < 4; j++) {
      acc1[i][j] = {0.f, 0.f, 0.f, 0.f};
      acc2[i][j] = {0.f, 0.f, 0.f, 0.f};
    }

  const int skk = tid & 63, smg = tid >> 6;  // A staging: k (q), m-group

  for (int k0 = 0; k0 < LQ; k0 += 64) {
    const float qm = qml[k0 + skk];
    // A: As[m][k] = S1[c0+m][k0+k]
#pragma unroll
    for (int i = 0; i < 16; ++i) {
      const int m = smg * 16 + i;
      const float sv = Sb[(size_t)m * LQ + k0 + skk];
      const float lg = sv * qm + (1.f - qm) * NEG_INF;
      sm.st.As[m][skk] = (bf16)(__expf(lg - rml[m]) * rsl[m]);
    }
    // B1: [n=d][k=q] from Q
#pragma unroll
    for (int p = 0; p < 8; ++p) {
      const int idx = p * 256 + tid;
      const int n = idx >> 4, kq = (idx & 15) * 4;
      const f32x4 v = *(const f32x4*)(Qb + (size_t)(nt + n) * LQ + k0 + kq);
      bf16x4 o = {(bf16)v[0], (bf16)v[1], (bf16)v[2], (bf16)v[3]};
      *(bf16x4*)(&sm.st.B1[n][kq]) = o;
    }
    // B2: [n=d][k=q] from Utb (already bf16)
#pragma unroll
    for (int p = 0; p < 4; ++p) {
      const int idx = p * 256 + tid;
      const int n = idx >> 3, kk = (idx & 7) * 8;
      *(bf16x8*)(&sm.st.B2[n][kk]) = *(const bf16x8*)(Ub + (size_t)(nt + n) * LQ + k0 + kk);
    }
    __syncthreads();
#pragma unroll
    for (int kk = 0; kk < 64; kk += 32) {
      bf16x8 af[2], b1f[4], b2f[4];
#pragma unroll
      for (int mi = 0; mi < 2; mi++)
        af[mi] = *(const bf16x8*)(&sm.st.As[wm + mi * 16 + (lane & 15)][kk + (lane >> 4) * 8]);
#pragma unroll
      for (int ni = 0; ni < 4; ni++) {
        b1f[ni] = *(const bf16x8*)(&sm.st.B1[wn + ni * 16 + (lane & 15)][kk + (lane >> 4) * 8]);
        b2f[ni] = *(const bf16x8*)(&sm.st.B2[wn + ni * 16 + (lane & 15)][kk + (lane >> 4) * 8]);
      }
#pragma unroll
      for (int mi = 0; mi < 2; mi++)
#pragma unroll
        for (int ni = 0; ni < 4; ni++) {
          acc1[mi][ni] = mfma16(af[mi], b1f[ni], acc1[mi][ni]);
          acc2[mi][ni] = mfma16(af[mi], b2f[ni], acc2[mi][ni]);
        }
    }
    __syncthreads();
  }

  // ---- epilogue: bounce acc through LDS, write 4 sections coalesced in c ----
  const int r4 = (lane >> 4) * 4, cn = lane & 15;
#pragma unroll
  for (int mi = 0; mi < 2; mi++)
#pragma unroll
    for (int ni = 0; ni < 4; ni++)
#pragma unroll
      for (int j = 0; j < 4; j++)
        sm.bounce[wm + mi * 16 + r4 + j][wn + ni * 16 + cn] = acc1[mi][ni][j];
  __syncthreads();

  const int ec = tid & 63, eg = tid >> 6;
  const size_t outB = (size_t)b * (4 * D_) * LC;
#pragma unroll 4
  for (int dr = eg; dr < 128; dr += 4) {
    const int d = nt + dr;
    const float av = sm.bounce[ec][dr];
    const float cv = Cb[(size_t)d * LC + c0 + ec];
    out[outB + (size_t)d * LC + c0 + ec] = cv;                       // Ct
    out[outB + (size_t)(D_ + d) * LC + c0 + ec] = av;                // A
    out[outB + (size_t)(2 * D_ + d) * LC + c0 + ec] = cv * av;       // Ct*A
  }
  __syncthreads();
#pragma unroll
  for (int mi = 0; mi < 2; mi++)
#pragma unroll
    for (int ni = 0; ni < 4; ni++)
#pragma unroll
      for (int j = 0; j < 4; j++)
        sm.bounce[wm + mi * 16 + r4 + j][wn + ni * 16 + cn] = acc2[mi][ni][j];
  __syncthreads();
#pragma unroll 4
  for (int dr = eg; dr < 128; dr += 4) {
    const int d = nt + dr;
    const float bv = sm.bounce[ec][dr];
    const float cv = Cb[(size_t)d * LC + c0 + ec];
    out[outB + (size_t)(3 * D_ + d) * LC + c0 + ec] = cv * bv;       // Ct*Bv
  }
}

// ---------------------------------------------------------------------------
extern "C" void kernel_launch(void* const* d_in, const int* in_sizes, int n_in,
                              void* d_out, int out_size, void* d_ws, size_t ws_size,
                              hipStream_t stream) {
  (void)in_sizes; (void)n_in; (void)out_size; (void)ws_size;
  const float* C = (const float*)d_in[0];
  const float* Q = (const float*)d_in[1];
  const float* cmask = (const float*)d_in[2];
  const float* qmask = (const float*)d_in[3];
  const float* w = (const float*)d_in[4];
  float* out = (float*)d_out;

  float* ws = (float*)d_ws;
  float* S = ws;                                   // B*LC*LQ
  float* rmaxg = S + (size_t)B_ * LC * LQ;         // B*LC
  float* rsumg = rmaxg + B_ * LC;                  // B*LC
  float* cpm = rsumg + B_ * LC;                    // B*32*LQ
  float* cps = cpm + B_ * 32 * LQ;                 // B*32*LQ
  float* cmaxg = cps + B_ * 32 * LQ;               // B*LQ
  float* csumg = cmaxg + B_ * LQ;                  // B*LQ
  float* bqg = csumg + B_ * LQ;                    // B*LQ
  bf16* Qtb = (bf16*)(bqg + B_ * LQ);              // B*LQ*D_ bf16
  bf16* Utb = Qtb + (size_t)B_ * LQ * D_;          // B*D_*LQ bf16

  qprep<<<dim3(16, B_), 256, 0, stream>>>(Q, Qtb);
  bqkern<<<dim3(B_), 256, 0, stream>>>(Q, w, bqg);
  k1_sgemm<<<dim3(LC / 64, B_), 256, 0, stream>>>(C, Qtb, w, cmask, qmask, bqg,
                                                  S, rmaxg, rsumg, cpm, cps);
  k2_colstats<<<dim3(B_), 256, 0, stream>>>(cpm, cps, cmaxg, csumg);
  k3_ugemm<<<dim3(4, B_), 256, 0, stream>>>(S, C, cmask, cmaxg, csumg, Utb);
  k4_final<<<dim3(64, B_), 256, 0, stream>>>(S, C, Q, Utb, qmask, rmaxg, rsumg, out);
}

// Round 2
// 385.975 us; speedup vs baseline: 1.3363x; 1.3363x over previous
//
#include <hip/hip_runtime.h>

// CQAttention fused pipeline for MI355X (gfx950).
// B=32, D=256, Lc=2048, Lq=256, fp32 in/out, bf16 MFMA internally.
// R2: S stored bf16 (stats computed on rounded values); k3 is split-K
// (4-way over Lc) + k3r reduce. Workspace ~75 MB.

#define B_ 32
#define D_ 256
#define LC 2048
#define LQ 256
#define KSPLIT 4
#define NEG_INF (-1e30f)

using bf16   = __bf16;
using bf16x4 = __attribute__((ext_vector_type(4))) __bf16;
using bf16x8 = __attribute__((ext_vector_type(8))) __bf16;
using f32x4  = __attribute__((ext_vector_type(4))) float;

static __device__ __forceinline__ f32x4 mfma16(bf16x8 a, bf16x8 b, f32x4 c) {
  return __builtin_amdgcn_mfma_f32_16x16x32_bf16(a, b, c, 0, 0, 0);
}

// ---------------------------------------------------------------------------
// K0a: transpose Q (b,d,q) f32 -> Qtb (b,q,d) bf16
// ---------------------------------------------------------------------------
__global__ __launch_bounds__(256) void qprep(const float* __restrict__ Q,
                                             bf16* __restrict__ Qtb) {
  __shared__ float t[64][65];
  const int b  = blockIdx.y;
  const int qt = (blockIdx.x >> 2) * 64;
  const int dt = (blockIdx.x & 3) * 64;
  const int c  = threadIdx.x & 63, r0 = threadIdx.x >> 6;
  const float* Qb = Q + (size_t)b * D_ * LQ;
#pragma unroll
  for (int r = r0; r < 64; r += 4) t[r][c] = Qb[(size_t)(dt + r) * LQ + qt + c];
  __syncthreads();
  bf16* O = Qtb + (size_t)b * LQ * D_;
#pragma unroll
  for (int r = r0; r < 64; r += 4)
    O[(size_t)(qt + r) * D_ + dt + c] = (bf16)t[c][r];  // Qtb[q][d] = Q[d][q]
}

// ---------------------------------------------------------------------------
// K0b: bq[b][q] = sum_d Q[b,d,q] * w2[d]
// ---------------------------------------------------------------------------
__global__ __launch_bounds__(256) void bqkern(const float* __restrict__ Q,
                                              const float* __restrict__ w,
                                              float* __restrict__ bq) {
  const int b = blockIdx.x, q = threadIdx.x;
  const float* Qb = Q + (size_t)b * D_ * LQ;
  float acc = 0.f;
  for (int d = 0; d < D_; ++d) acc += Qb[(size_t)d * LQ + q] * w[D_ + d];
  bq[b * LQ + q] = acc;
}

// ---------------------------------------------------------------------------
// K1: S = (C*w3)^T @ Q + a[c] + bq[q]  -> bf16 S (rounded), stats computed on
// the ROUNDED values so downstream recomputation is consistent.
// Tile: BM=64 (c) x BN=256 (q, full) x K=256 (d), BK=64. 4 waves, n-split.
// ---------------------------------------------------------------------------
__global__ __launch_bounds__(256) void k1_sgemm(
    const float* __restrict__ C, const bf16* __restrict__ Qtb,
    const float* __restrict__ w, const float* __restrict__ cmask,
    const float* __restrict__ qmask, const float* __restrict__ bq,
    bf16* __restrict__ S, float* __restrict__ rmaxg, float* __restrict__ rsumg,
    float* __restrict__ cpmax, float* __restrict__ cpsum) {
  __shared__ __align__(16) bf16 As[64][72];
  __shared__ __align__(16) bf16 Bs[256][72];
  __shared__ float ared[4][64];
  __shared__ float wred[4][64];
  __shared__ float wsum[4][64];
  __shared__ float cml[64];
  __shared__ float qml[256];
  __shared__ float bql[256];

  const int b = blockIdx.y, ct = blockIdx.x, c0 = ct * 64;
  const int tid = threadIdx.x, lane = tid & 63, wv = tid >> 6;
  const float* Cb = C + (size_t)b * D_ * LC;
  const bf16* Qt = Qtb + (size_t)b * LQ * D_;
  const float* w1 = w;
  const float* w3 = w + 2 * D_;

  if (tid < 64) cml[tid] = cmask[b * LC + c0 + tid];
  qml[tid] = qmask[b * LQ + tid];
  bql[tid] = bq[b * LQ + tid];

  f32x4 acc[4][4];
#pragma unroll
  for (int i = 0; i < 4; i++)
#pragma unroll
    for (int j = 0; j < 4; j++) acc[i][j] = {0.f, 0.f, 0.f, 0.f};
  float acc_a = 0.f;

  const int sm = tid & 63;   // staging: m (c)
  const int skg = tid >> 6;  // staging: k-group

  for (int k0 = 0; k0 < D_; k0 += 64) {
    // A-tile: As[m][k] = C[b][k0+k][c0+m] * w3 ; fold a-bias accumulation.
#pragma unroll
    for (int i = 0; i < 16; ++i) {
      const int k = skg * 16 + i, kg = k0 + k;
      const float v = Cb[(size_t)kg * LC + c0 + sm];
      As[sm][k] = (bf16)(v * w3[kg]);
      acc_a += v * w1[kg];
    }
    // B-tile: Bs[q][k] = Qtb[b][q][k0+k]  (256 x 64 bf16)
#pragma unroll
    for (int p = 0; p < 8; ++p) {
      const int idx = (p * 256 + tid) * 8;
      const int q = idx >> 6, kk = idx & 63;
      *(bf16x8*)(&Bs[q][kk]) = *(const bf16x8*)(Qt + (size_t)q * D_ + k0 + kk);
    }
    __syncthreads();
#pragma unroll
    for (int kk = 0; kk < 64; kk += 32) {
      bf16x8 af[4], bfr[4];
#pragma unroll
      for (int mi = 0; mi < 4; mi++)
        af[mi] = *(const bf16x8*)(&As[mi * 16 + (lane & 15)][kk + (lane >> 4) * 8]);
#pragma unroll
      for (int ni = 0; ni < 4; ni++)
        bfr[ni] = *(const bf16x8*)(&Bs[wv * 64 + ni * 16 + (lane & 15)][kk + (lane >> 4) * 8]);
#pragma unroll
      for (int mi = 0; mi < 4; mi++)
#pragma unroll
        for (int ni = 0; ni < 4; ni++)
          acc[mi][ni] = mfma16(af[mi], bfr[ni], acc[mi][ni]);
    }
    __syncthreads();
  }

  ared[skg][sm] = acc_a;
  __syncthreads();

  const int r4 = (lane >> 4) * 4;  // fragment row base
  const int cn = lane & 15;        // fragment col

  // acc <- raw S = gemm + a[c] + bq[q]; round to bf16; store; keep rounded.
  bf16* Sb = S + ((size_t)b * LC + c0) * LQ;
#pragma unroll
  for (int mi = 0; mi < 4; mi++)
#pragma unroll
    for (int j = 0; j < 4; j++) {
      const int m = mi * 16 + r4 + j;
      const float aval = ared[0][m] + ared[1][m] + ared[2][m] + ared[3][m];
#pragma unroll
      for (int ni = 0; ni < 4; ni++) {
        const int n = wv * 64 + ni * 16 + cn;
        const bf16 sb = (bf16)(acc[mi][ni][j] + aval + bql[n]);
        Sb[(size_t)m * LQ + n] = sb;
        acc[mi][ni][j] = (float)sb;  // rounded value for stats
      }
    }

  // ---- row stats (softmax over q, qmask logits) ----
  float gmx[4][4];
#pragma unroll
  for (int mi = 0; mi < 4; mi++)
#pragma unroll
    for (int j = 0; j < 4; j++) {
      float mx = -3.0e38f;
#pragma unroll
      for (int ni = 0; ni < 4; ni++) {
        const int n = wv * 64 + ni * 16 + cn;
        const float qm = qml[n];
        const float lg = acc[mi][ni][j] * qm + (1.f - qm) * NEG_INF;
        mx = fmaxf(mx, lg);
      }
      for (int s = 1; s < 16; s <<= 1) mx = fmaxf(mx, __shfl_xor(mx, s));
      if (cn == 0) wred[wv][mi * 16 + r4 + j] = mx;
    }
  __syncthreads();
#pragma unroll
  for (int mi = 0; mi < 4; mi++)
#pragma unroll
    for (int j = 0; j < 4; j++) {
      const int m = mi * 16 + r4 + j;
      gmx[mi][j] = fmaxf(fmaxf(wred[0][m], wred[1][m]), fmaxf(wred[2][m], wred[3][m]));
      float ps = 0.f;
#pragma unroll
      for (int ni = 0; ni < 4; ni++) {
        const int n = wv * 64 + ni * 16 + cn;
        const float qm = qml[n];
        const float lg = acc[mi][ni][j] * qm + (1.f - qm) * NEG_INF;
        ps += __expf(lg - gmx[mi][j]);
      }
      for (int s = 1; s < 16; s <<= 1) ps += __shfl_xor(ps, s);
      if (cn == 0) wsum[wv][m] = ps;
    }
  __syncthreads();
  if (tid < 64) {
    const int m = tid;
    const float rm = fmaxf(fmaxf(wred[0][m], wred[1][m]), fmaxf(wred[2][m], wred[3][m]));
    const float rs = wsum[0][m] + wsum[1][m] + wsum[2][m] + wsum[3][m];
    rmaxg[b * LC + c0 + m] = rm;
    rsumg[b * LC + c0 + m] = rs;
  }

  // ---- column partial stats over this 64-row tile (cmask logits) ----
#pragma unroll
  for (int ni = 0; ni < 4; ni++) {
    const int n = wv * 64 + ni * 16 + cn;
    float mx = -3.0e38f;
#pragma unroll
    for (int mi = 0; mi < 4; mi++)
#pragma unroll
      for (int j = 0; j < 4; j++) {
        const int m = mi * 16 + r4 + j;
        const float cmv = cml[m];
        const float lg = acc[mi][ni][j] * cmv + (1.f - cmv) * NEG_INF;
        mx = fmaxf(mx, lg);
      }
    mx = fmaxf(mx, __shfl_xor(mx, 16));
    mx = fmaxf(mx, __shfl_xor(mx, 32));
    float ps = 0.f;
#pragma unroll
    for (int mi = 0; mi < 4; mi++)
#pragma unroll
      for (int j = 0; j < 4; j++) {
        const int m = mi * 16 + r4 + j;
        const float cmv = cml[m];
        const float lg = acc[mi][ni][j] * cmv + (1.f - cmv) * NEG_INF;
        ps += __expf(lg - mx);
      }
    ps += __shfl_xor(ps, 16);
    ps += __shfl_xor(ps, 32);
    if ((lane >> 4) == 0) {
      cpmax[((size_t)(b * 32 + ct)) * LQ + n] = mx;
      cpsum[((size_t)(b * 32 + ct)) * LQ + n] = ps;
    }
  }
}

// ---------------------------------------------------------------------------
// K2: combine 32 column-partial stats -> cmax/csum per (b,q). Exact merge.
// ---------------------------------------------------------------------------
__global__ __launch_bounds__(256) void k2_colstats(const float* __restrict__ cpmax,
                                                   const float* __restrict__ cpsum,
                                                   float* __restrict__ cmaxg,
                                                   float* __restrict__ csumg) {
  const int b = blockIdx.x, q = threadIdx.x;
  float m = -3.0e38f;
  for (int t = 0; t < 32; t++) m = fmaxf(m, cpmax[(size_t)(b * 32 + t) * LQ + q]);
  float s = 0.f;
  for (int t = 0; t < 32; t++)
    s += cpsum[(size_t)(b * 32 + t) * LQ + q] * __expf(cpmax[(size_t)(b * 32 + t) * LQ + q] - m);
  cmaxg[b * LQ + q] = m;
  csumg[b * LQ + q] = s;
}

// ---------------------------------------------------------------------------
// K3: U[q,d] = sum_c S2[c,q] * Ct[c,d] — SPLIT-K over Lc (4 chunks of 512).
// Tile: 128(q) x 128(d) per block; grid 16/b: {ks(4), q-tile(2), d-tile(2)}.
// Writes fp32 partials Up[ks][b][d][q] (transposed layout for the reduce).
// ---------------------------------------------------------------------------
__global__ __launch_bounds__(256) void k3_ugemm(
    const bf16* __restrict__ S, const float* __restrict__ C,
    const float* __restrict__ cmask, const float* __restrict__ cmaxg,
    const float* __restrict__ csumg, float* __restrict__ Up) {
  __shared__ __align__(16) bf16 As[128][72];
  __shared__ __align__(16) bf16 Bs[128][72];
  const int b = blockIdx.y;
  const int ks = blockIdx.x >> 2;
  const int mt = ((blockIdx.x >> 1) & 1) * 128;  // q offset
  const int nt = (blockIdx.x & 1) * 128;         // d offset
  const int cbase = ks * (LC / KSPLIT);
  const int tid = threadIdx.x, lane = tid & 63, wv = tid >> 6;
  const int wm = (wv >> 1) * 64, wn = (wv & 1) * 64;

  const bf16* Sb = S + (size_t)b * LC * LQ;
  const float* Cb = C + (size_t)b * D_ * LC;

  const int am = tid & 127, akh = tid >> 7;  // A staging: m (q), k-half
  const float cmx = cmaxg[b * LQ + mt + am];
  const float csv = 1.0f / csumg[b * LQ + mt + am];

  f32x4 acc[4][4];
#pragma unroll
  for (int i = 0; i < 4; i++)
#pragma unroll
    for (int j = 0; j < 4; j++) acc[i][j] = {0.f, 0.f, 0.f, 0.f};

  for (int k0 = 0; k0 < LC / KSPLIT; k0 += 64) {
    // A: As[m][k] = S2[c=cbase+k0+k][q=mt+m]
#pragma unroll
    for (int i = 0; i < 32; ++i) {
      const int k = akh * 32 + i, c = cbase + k0 + k;
      const float cmv = cmask[b * LC + c];
      const float sv = (float)Sb[(size_t)c * LQ + mt + am];
      const float lg = sv * cmv + (1.f - cmv) * NEG_INF;
      As[am][k] = (bf16)(__expf(lg - cmx) * csv);
    }
    // B: Bs[n][k] = Ct[c][d=nt+n] = C[b][nt+n][cbase+k0+k]
#pragma unroll
    for (int p = 0; p < 8; ++p) {
      const int idx = p * 256 + tid;
      const int n = idx >> 4, kq = (idx & 15) * 4;
      const f32x4 v = *(const f32x4*)(Cb + (size_t)(nt + n) * LC + cbase + k0 + kq);
      bf16x4 o = {(bf16)v[0], (bf16)v[1], (bf16)v[2], (bf16)v[3]};
      *(bf16x4*)(&Bs[n][kq]) = o;
    }
    __syncthreads();
#pragma unroll
    for (int kk = 0; kk < 64; kk += 32) {
      bf16x8 af[4], bfr[4];
#pragma unroll
      for (int mi = 0; mi < 4; mi++)
        af[mi] = *(const bf16x8*)(&As[wm + mi * 16 + (lane & 15)][kk + (lane >> 4) * 8]);
#pragma unroll
      for (int ni = 0; ni < 4; ni++)
        bfr[ni] = *(const bf16x8*)(&Bs[wn + ni * 16 + (lane & 15)][kk + (lane >> 4) * 8]);
#pragma unroll
      for (int mi = 0; mi < 4; mi++)
#pragma unroll
        for (int ni = 0; ni < 4; ni++)
          acc[mi][ni] = mfma16(af[mi], bfr[ni], acc[mi][ni]);
    }
    __syncthreads();
  }

  // store fp32 partials Up[ks][b][d][q] (4 consecutive q per lane -> f32x4)
  float* Ub = Up + ((size_t)(ks * B_ + b)) * D_ * LQ;
#pragma unroll
  for (int mi = 0; mi < 4; mi++)
#pragma unroll
    for (int ni = 0; ni < 4; ni++) {
      const int q = mt + wm + mi * 16 + (lane >> 4) * 4;
      const int d = nt + wn + ni * 16 + (lane & 15);
      *(f32x4*)(Ub + (size_t)d * LQ + q) = acc[mi][ni];
    }
}

// ---------------------------------------------------------------------------
// K3r: Utb[b][d][q] = bf16( sum_ks Up[ks][b][d][q] )
// ---------------------------------------------------------------------------
__global__ __launch_bounds__(256) void k3r_reduce(const float* __restrict__ Up,
                                                  bf16* __restrict__ Utb) {
  const size_t NP = (size_t)B_ * D_ * LQ;
  const size_t i4 = ((size_t)blockIdx.x * 256 + threadIdx.x) * 4;
  f32x4 s = *(const f32x4*)(Up + i4);
#pragma unroll
  for (int p = 1; p < KSPLIT; ++p) {
    const f32x4 v = *(const f32x4*)(Up + p * NP + i4);
    s[0] += v[0]; s[1] += v[1]; s[2] += v[2]; s[3] += v[3];
  }
  bf16x4 o = {(bf16)s[0], (bf16)s[1], (bf16)s[2], (bf16)s[3]};
  *(bf16x4*)(Utb + i4) = o;
}

// ---------------------------------------------------------------------------
// K4: A = S1 @ Qt, Bv = S1 @ U (shared S1 tiles); emit all 4 output sections.
// Tile: BM=64 (c) x BN=128 (d), K=256 (q), BK=64. Waves 2x2 (32x64 each).
// ---------------------------------------------------------------------------
__global__ __launch_bounds__(256) void k4_final(
    const bf16* __restrict__ S, const float* __restrict__ C,
    const float* __restrict__ Q, const bf16* __restrict__ Utb,
    const float* __restrict__ qmask, const float* __restrict__ rmaxg,
    const float* __restrict__ rsumg, float* __restrict__ out) {
  union __align__(16) Sm {
    struct {
      bf16 As[64][72];
      bf16 B1[128][72];
      bf16 B2[128][72];
    } st;
    float bounce[64][129];
  };
  __shared__ Sm sm;
  __shared__ float rml[64], rsl[64], qml[256];

  const int b = blockIdx.y;
  const int ct = blockIdx.x >> 1, c0 = ct * 64;
  const int nt = (blockIdx.x & 1) * 128;
  const int tid = threadIdx.x, lane = tid & 63, wv = tid >> 6;
  const int wm = (wv >> 1) * 32, wn = (wv & 1) * 64;

  if (tid < 64) {
    rml[tid] = rmaxg[b * LC + c0 + tid];
    rsl[tid] = 1.0f / rsumg[b * LC + c0 + tid];
  }
  qml[tid] = qmask[b * LQ + tid];
  __syncthreads();

  const bf16* Sb = S + ((size_t)b * LC + c0) * LQ;
  const float* Cb = C + (size_t)b * D_ * LC;
  const float* Qb = Q + (size_t)b * D_ * LQ;
  const bf16* Ub = Utb + (size_t)b * D_ * LQ;

  f32x4 acc1[2][4], acc2[2][4];
#pragma unroll
  for (int i = 0; i < 2; i++)
#pragma unroll
    for (int j = 0; j < 4; j++) {
      acc1[i][j] = {0.f, 0.f, 0.f, 0.f};
      acc2[i][j] = {0.f, 0.f, 0.f, 0.f};
    }

  const int skk = tid & 63, smg = tid >> 6;  // A staging: k (q), m-group

  for (int k0 = 0; k0 < LQ; k0 += 64) {
    const float qm = qml[k0 + skk];
    // A: As[m][k] = S1[c0+m][k0+k]
#pragma unroll
    for (int i = 0; i < 16; ++i) {
      const int m = smg * 16 + i;
      const float sv = (float)Sb[(size_t)m * LQ + k0 + skk];
      const float lg = sv * qm + (1.f - qm) * NEG_INF;
      sm.st.As[m][skk] = (bf16)(__expf(lg - rml[m]) * rsl[m]);
    }
    // B1: [n=d][k=q] from Q
#pragma unroll
    for (int p = 0; p < 8; ++p) {
      const int idx = p * 256 + tid;
      const int n = idx >> 4, kq = (idx & 15) * 4;
      const f32x4 v = *(const f32x4*)(Qb + (size_t)(nt + n) * LQ + k0 + kq);
      bf16x4 o = {(bf16)v[0], (bf16)v[1], (bf16)v[2], (bf16)v[3]};
      *(bf16x4*)(&sm.st.B1[n][kq]) = o;
    }
    // B2: [n=d][k=q] from Utb (already bf16)
#pragma unroll
    for (int p = 0; p < 4; ++p) {
      const int idx = p * 256 + tid;
      const int n = idx >> 3, kk = (idx & 7) * 8;
      *(bf16x8*)(&sm.st.B2[n][kk]) = *(const bf16x8*)(Ub + (size_t)(nt + n) * LQ + k0 + kk);
    }
    __syncthreads();
#pragma unroll
    for (int kk = 0; kk < 64; kk += 32) {
      bf16x8 af[2], b1f[4], b2f[4];
#pragma unroll
      for (int mi = 0; mi < 2; mi++)
        af[mi] = *(const bf16x8*)(&sm.st.As[wm + mi * 16 + (lane & 15)][kk + (lane >> 4) * 8]);
#pragma unroll
      for (int ni = 0; ni < 4; ni++) {
        b1f[ni] = *(const bf16x8*)(&sm.st.B1[wn + ni * 16 + (lane & 15)][kk + (lane >> 4) * 8]);
        b2f[ni] = *(const bf16x8*)(&sm.st.B2[wn + ni * 16 + (lane & 15)][kk + (lane >> 4) * 8]);
      }
#pragma unroll
      for (int mi = 0; mi < 2; mi++)
#pragma unroll
        for (int ni = 0; ni < 4; ni++) {
          acc1[mi][ni] = mfma16(af[mi], b1f[ni], acc1[mi][ni]);
          acc2[mi][ni] = mfma16(af[mi], b2f[ni], acc2[mi][ni]);
        }
    }
    __syncthreads();
  }

  // ---- epilogue: bounce acc through LDS, write 4 sections coalesced in c ----
  const int r4 = (lane >> 4) * 4, cn = lane & 15;
#pragma unroll
  for (int mi = 0; mi < 2; mi++)
#pragma unroll
    for (int ni = 0; ni < 4; ni++)
#pragma unroll
      for (int j = 0; j < 4; j++)
        sm.bounce[wm + mi * 16 + r4 + j][wn + ni * 16 + cn] = acc1[mi][ni][j];
  __syncthreads();

  const int ec = tid & 63, eg = tid >> 6;
  const size_t outB = (size_t)b * (4 * D_) * LC;
#pragma unroll 4
  for (int dr = eg; dr < 128; dr += 4) {
    const int d = nt + dr;
    const float av = sm.bounce[ec][dr];
    const float cv = Cb[(size_t)d * LC + c0 + ec];
    out[outB + (size_t)d * LC + c0 + ec] = cv;                       // Ct
    out[outB + (size_t)(D_ + d) * LC + c0 + ec] = av;                // A
    out[outB + (size_t)(2 * D_ + d) * LC + c0 + ec] = cv * av;       // Ct*A
  }
  __syncthreads();
#pragma unroll
  for (int mi = 0; mi < 2; mi++)
#pragma unroll
    for (int ni = 0; ni < 4; ni++)
#pragma unroll
      for (int j = 0; j < 4; j++)
        sm.bounce[wm + mi * 16 + r4 + j][wn + ni * 16 + cn] = acc2[mi][ni][j];
  __syncthreads();
#pragma unroll 4
  for (int dr = eg; dr < 128; dr += 4) {
    const int d = nt + dr;
    const float bv = sm.bounce[ec][dr];
    const float cv = Cb[(size_t)d * LC + c0 + ec];
    out[outB + (size_t)(3 * D_ + d) * LC + c0 + ec] = cv * bv;       // Ct*Bv
  }
}

// ---------------------------------------------------------------------------
extern "C" void kernel_launch(void* const* d_in, const int* in_sizes, int n_in,
                              void* d_out, int out_size, void* d_ws, size_t ws_size,
                              hipStream_t stream) {
  (void)in_sizes; (void)n_in; (void)out_size; (void)ws_size;
  const float* C = (const float*)d_in[0];
  const float* Q = (const float*)d_in[1];
  const float* cmask = (const float*)d_in[2];
  const float* qmask = (const float*)d_in[3];
  const float* w = (const float*)d_in[4];
  float* out = (float*)d_out;

  float* ws = (float*)d_ws;
  float* Up = ws;                                   // KSPLIT*B*D*LQ fp32 (32MB)
  float* rmaxg = Up + (size_t)KSPLIT * B_ * D_ * LQ;
  float* rsumg = rmaxg + B_ * LC;
  float* cpm = rsumg + B_ * LC;                     // B*32*LQ
  float* cps = cpm + B_ * 32 * LQ;
  float* cmaxg = cps + B_ * 32 * LQ;
  float* csumg = cmaxg + B_ * LQ;
  float* bqg = csumg + B_ * LQ;
  bf16* Sb16 = (bf16*)(bqg + B_ * LQ);              // B*LC*LQ bf16 (32MB)
  bf16* Qtb = Sb16 + (size_t)B_ * LC * LQ;          // B*LQ*D_ bf16
  bf16* Utb = Qtb + (size_t)B_ * LQ * D_;           // B*D_*LQ bf16

  qprep<<<dim3(16, B_), 256, 0, stream>>>(Q, Qtb);
  bqkern<<<dim3(B_), 256, 0, stream>>>(Q, w, bqg);
  k1_sgemm<<<dim3(LC / 64, B_), 256, 0, stream>>>(C, Qtb, w, cmask, qmask, bqg,
                                                  Sb16, rmaxg, rsumg, cpm, cps);
  k2_colstats<<<dim3(B_), 256, 0, stream>>>(cpm, cps, cmaxg, csumg);
  k3_ugemm<<<dim3(16, B_), 256, 0, stream>>>(Sb16, C, cmask, cmaxg, csumg, Up);
  k3r_reduce<<<dim3((B_ * D_ * LQ) / 1024), 256, 0, stream>>>(Up, Utb);
  k4_final<<<dim3(64, B_), 256, 0, stream>>>(Sb16, C, Q, Utb, qmask, rmaxg, rsumg, out);
}

// Round 3
// 343.389 us; speedup vs baseline: 1.5020x; 1.1240x over previous
//
#include <hip/hip_runtime.h>

// CQAttention fused pipeline for MI355X (gfx950).
// B=32, D=256, Lc=2048, Lq=256, fp32 in/out, bf16 MFMA internally.
// R3: k1 emits S1 (row-softmaxed, bf16, [c][q]) + raw S^T (bf16, [q][c]).
// k3/k4 are barrier-free register-fragment GEMMs (no LDS staging).
// Workspace ~102 MB.

#define B_ 32
#define D_ 256
#define LC 2048
#define LQ 256
#define KSPLIT 4
#define NEG_INF (-1e30f)

using bf16   = __bf16;
using bf16x4 = __attribute__((ext_vector_type(4))) __bf16;
using bf16x8 = __attribute__((ext_vector_type(8))) __bf16;
using f32x4  = __attribute__((ext_vector_type(4))) float;

static __device__ __forceinline__ f32x4 mfma16(bf16x8 a, bf16x8 b, f32x4 c) {
  return __builtin_amdgcn_mfma_f32_16x16x32_bf16(a, b, c, 0, 0, 0);
}

// ---------------------------------------------------------------------------
// K0a: transpose Q (b,d,q) f32 -> Qtb (b,q,d) bf16
// ---------------------------------------------------------------------------
__global__ __launch_bounds__(256) void qprep(const float* __restrict__ Q,
                                             bf16* __restrict__ Qtb) {
  __shared__ float t[64][65];
  const int b  = blockIdx.y;
  const int qt = (blockIdx.x >> 2) * 64;
  const int dt = (blockIdx.x & 3) * 64;
  const int c  = threadIdx.x & 63, r0 = threadIdx.x >> 6;
  const float* Qb = Q + (size_t)b * D_ * LQ;
#pragma unroll
  for (int r = r0; r < 64; r += 4) t[r][c] = Qb[(size_t)(dt + r) * LQ + qt + c];
  __syncthreads();
  bf16* O = Qtb + (size_t)b * LQ * D_;
#pragma unroll
  for (int r = r0; r < 64; r += 4)
    O[(size_t)(qt + r) * D_ + dt + c] = (bf16)t[c][r];  // Qtb[q][d] = Q[d][q]
}

// ---------------------------------------------------------------------------
// K0b: bq[b][q] = sum_d Q[b,d,q] * w2[d]
// ---------------------------------------------------------------------------
__global__ __launch_bounds__(256) void bqkern(const float* __restrict__ Q,
                                              const float* __restrict__ w,
                                              float* __restrict__ bq) {
  const int b = blockIdx.x, q = threadIdx.x;
  const float* Qb = Q + (size_t)b * D_ * LQ;
  float acc = 0.f;
  for (int d = 0; d < D_; ++d) acc += Qb[(size_t)d * LQ + q] * w[D_ + d];
  bq[b * LQ + q] = acc;
}

// ---------------------------------------------------------------------------
// K1: S = (C*w3)^T @ Q + a[c] + bq[q], rounded to bf16.
// Emits: S1[c][q] bf16 (row-softmaxed with qmask), St[q][c] bf16 (raw,
// transposed via LDS bounce), and per-tile column partial stats.
// ---------------------------------------------------------------------------
__global__ __launch_bounds__(256) void k1_sgemm(
    const float* __restrict__ C, const bf16* __restrict__ Qtb,
    const float* __restrict__ w, const float* __restrict__ cmask,
    const float* __restrict__ qmask, const float* __restrict__ bq,
    bf16* __restrict__ S1, bf16* __restrict__ St,
    float* __restrict__ cpmax, float* __restrict__ cpsum) {
  __shared__ __align__(16) bf16 As[64][72];
  __shared__ __align__(16) bf16 Bs[256][72];  // reused as St bounce after loop
  __shared__ float ared[4][64];               // [0]/[1] reused as rml/rsl
  __shared__ float wred[4][64];
  __shared__ float wsum[4][64];
  __shared__ float cml[64];
  __shared__ float qml[256];
  __shared__ float bql[256];

  const int b = blockIdx.y, ct = blockIdx.x, c0 = ct * 64;
  const int tid = threadIdx.x, lane = tid & 63, wv = tid >> 6;
  const float* Cb = C + (size_t)b * D_ * LC;
  const bf16* Qt = Qtb + (size_t)b * LQ * D_;
  const float* w1 = w;
  const float* w3 = w + 2 * D_;

  if (tid < 64) cml[tid] = cmask[b * LC + c0 + tid];
  qml[tid] = qmask[b * LQ + tid];
  bql[tid] = bq[b * LQ + tid];

  f32x4 acc[4][4];
#pragma unroll
  for (int i = 0; i < 4; i++)
#pragma unroll
    for (int j = 0; j < 4; j++) acc[i][j] = {0.f, 0.f, 0.f, 0.f};
  float acc_a = 0.f;

  const int sm = tid & 63;   // staging: m (c)
  const int skg = tid >> 6;  // staging: k-group

  for (int k0 = 0; k0 < D_; k0 += 64) {
#pragma unroll
    for (int i = 0; i < 16; ++i) {
      const int k = skg * 16 + i, kg = k0 + k;
      const float v = Cb[(size_t)kg * LC + c0 + sm];
      As[sm][k] = (bf16)(v * w3[kg]);
      acc_a += v * w1[kg];
    }
#pragma unroll
    for (int p = 0; p < 8; ++p) {
      const int idx = (p * 256 + tid) * 8;
      const int q = idx >> 6, kk = idx & 63;
      *(bf16x8*)(&Bs[q][kk]) = *(const bf16x8*)(Qt + (size_t)q * D_ + k0 + kk);
    }
    __syncthreads();
#pragma unroll
    for (int kk = 0; kk < 64; kk += 32) {
      bf16x8 af[4], bfr[4];
#pragma unroll
      for (int mi = 0; mi < 4; mi++)
        af[mi] = *(const bf16x8*)(&As[mi * 16 + (lane & 15)][kk + (lane >> 4) * 8]);
#pragma unroll
      for (int ni = 0; ni < 4; ni++)
        bfr[ni] = *(const bf16x8*)(&Bs[wv * 64 + ni * 16 + (lane & 15)][kk + (lane >> 4) * 8]);
#pragma unroll
      for (int mi = 0; mi < 4; mi++)
#pragma unroll
        for (int ni = 0; ni < 4; ni++)
          acc[mi][ni] = mfma16(af[mi], bfr[ni], acc[mi][ni]);
    }
    __syncthreads();
  }

  ared[skg][sm] = acc_a;
  __syncthreads();

  const int r4 = (lane >> 4) * 4;  // fragment row base
  const int cn = lane & 15;        // fragment col

  // acc <- raw S rounded to bf16 (kept as floats of rounded values)
#pragma unroll
  for (int mi = 0; mi < 4; mi++)
#pragma unroll
    for (int j = 0; j < 4; j++) {
      const int m = mi * 16 + r4 + j;
      const float aval = ared[0][m] + ared[1][m] + ared[2][m] + ared[3][m];
#pragma unroll
      for (int ni = 0; ni < 4; ni++) {
        const int n = wv * 64 + ni * 16 + cn;
        const bf16 sb = (bf16)(acc[mi][ni][j] + aval + bql[n]);
        acc[mi][ni][j] = (float)sb;
      }
    }
  __syncthreads();  // ared reads done; will reuse ared[0]/[1] below

  // ---- row stats (softmax over q, qmask logits) ----
#pragma unroll
  for (int mi = 0; mi < 4; mi++)
#pragma unroll
    for (int j = 0; j < 4; j++) {
      float mx = -3.0e38f;
#pragma unroll
      for (int ni = 0; ni < 4; ni++) {
        const int n = wv * 64 + ni * 16 + cn;
        const float qm = qml[n];
        const float lg = acc[mi][ni][j] * qm + (1.f - qm) * NEG_INF;
        mx = fmaxf(mx, lg);
      }
      for (int s = 1; s < 16; s <<= 1) mx = fmaxf(mx, __shfl_xor(mx, s));
      if (cn == 0) wred[wv][mi * 16 + r4 + j] = mx;
    }
  __syncthreads();
#pragma unroll
  for (int mi = 0; mi < 4; mi++)
#pragma unroll
    for (int j = 0; j < 4; j++) {
      const int m = mi * 16 + r4 + j;
      const float gm = fmaxf(fmaxf(wred[0][m], wred[1][m]), fmaxf(wred[2][m], wred[3][m]));
      float ps = 0.f;
#pragma unroll
      for (int ni = 0; ni < 4; ni++) {
        const int n = wv * 64 + ni * 16 + cn;
        const float qm = qml[n];
        const float lg = acc[mi][ni][j] * qm + (1.f - qm) * NEG_INF;
        ps += __expf(lg - gm);
      }
      for (int s = 1; s < 16; s <<= 1) ps += __shfl_xor(ps, s);
      if (cn == 0) wsum[wv][m] = ps;
    }
  __syncthreads();
  if (tid < 64) {
    const int m = tid;
    const float rm = fmaxf(fmaxf(wred[0][m], wred[1][m]), fmaxf(wred[2][m], wred[3][m]));
    const float rs = wsum[0][m] + wsum[1][m] + wsum[2][m] + wsum[3][m];
    ared[0][m] = rm;          // rml
    ared[1][m] = 1.0f / rs;   // rsl
  }
  __syncthreads();

  // ---- write S1 = exp(masked - rm) * rsl, bf16, [c][q] ----
  bf16* S1b = S1 + ((size_t)b * LC + c0) * LQ;
#pragma unroll
  for (int mi = 0; mi < 4; mi++)
#pragma unroll
    for (int j = 0; j < 4; j++) {
      const int m = mi * 16 + r4 + j;
      const float rm = ared[0][m], rs = ared[1][m];
#pragma unroll
      for (int ni = 0; ni < 4; ni++) {
        const int n = wv * 64 + ni * 16 + cn;
        const float qm = qml[n];
        const float lg = acc[mi][ni][j] * qm + (1.f - qm) * NEG_INF;
        S1b[(size_t)m * LQ + n] = (bf16)(__expf(lg - rm) * rs);
      }
    }

  // ---- column partial stats over this 64-row tile (cmask logits) ----
#pragma unroll
  for (int ni = 0; ni < 4; ni++) {
    const int n = wv * 64 + ni * 16 + cn;
    float mx = -3.0e38f;
#pragma unroll
    for (int mi = 0; mi < 4; mi++)
#pragma unroll
      for (int j = 0; j < 4; j++) {
        const int m = mi * 16 + r4 + j;
        const float cmv = cml[m];
        const float lg = acc[mi][ni][j] * cmv + (1.f - cmv) * NEG_INF;
        mx = fmaxf(mx, lg);
      }
    mx = fmaxf(mx, __shfl_xor(mx, 16));
    mx = fmaxf(mx, __shfl_xor(mx, 32));
    float ps = 0.f;
#pragma unroll
    for (int mi = 0; mi < 4; mi++)
#pragma unroll
      for (int j = 0; j < 4; j++) {
        const int m = mi * 16 + r4 + j;
        const float cmv = cml[m];
        const float lg = acc[mi][ni][j] * cmv + (1.f - cmv) * NEG_INF;
        ps += __expf(lg - mx);
      }
    ps += __shfl_xor(ps, 16);
    ps += __shfl_xor(ps, 32);
    if ((lane >> 4) == 0) {
      cpmax[((size_t)(b * 32 + ct)) * LQ + n] = mx;
      cpsum[((size_t)(b * 32 + ct)) * LQ + n] = ps;
    }
  }

  // ---- bounce raw S through Bs -> write St[q][c0..c0+64) coalesced ----
  __syncthreads();
#pragma unroll
  for (int mi = 0; mi < 4; mi++)
#pragma unroll
    for (int ni = 0; ni < 4; ni++)
#pragma unroll
      for (int j = 0; j < 4; j++) {
        const int m = mi * 16 + r4 + j;
        const int n = wv * 64 + ni * 16 + cn;
        Bs[n][m] = (bf16)acc[mi][ni][j];
      }
  __syncthreads();
  bf16* dst = St + ((size_t)b * LQ + tid) * LC + c0;
#pragma unroll
  for (int jj = 0; jj < 8; ++jj)
    *(bf16x8*)(dst + jj * 8) = *(const bf16x8*)(&Bs[tid][jj * 8]);
}

// ---------------------------------------------------------------------------
// K2: combine 32 column-partial stats -> cmax/csum per (b,q). Exact merge.
// ---------------------------------------------------------------------------
__global__ __launch_bounds__(256) void k2_colstats(const float* __restrict__ cpmax,
                                                   const float* __restrict__ cpsum,
                                                   float* __restrict__ cmaxg,
                                                   float* __restrict__ csumg) {
  const int b = blockIdx.x, q = threadIdx.x;
  float m = -3.0e38f;
  for (int t = 0; t < 32; t++) m = fmaxf(m, cpmax[(size_t)(b * 32 + t) * LQ + q]);
  float s = 0.f;
  for (int t = 0; t < 32; t++)
    s += cpsum[(size_t)(b * 32 + t) * LQ + q] * __expf(cpmax[(size_t)(b * 32 + t) * LQ + q] - m);
  cmaxg[b * LQ + q] = m;
  csumg[b * LQ + q] = s;
}

// ---------------------------------------------------------------------------
// K3: U[q,d] = sum_c S2[c,q]*Ct[c,d] — split-K over Lc, register-fragment
// GEMM (no LDS, no barriers). A from St[q][c] + on-the-fly S2 transform;
// B from C[d][c] (f32->bf16). Writes fp32 partials Up[ks][b][d][q].
// ---------------------------------------------------------------------------
__global__ __launch_bounds__(256) void k3_ugemm(
    const bf16* __restrict__ St, const float* __restrict__ C,
    const float* __restrict__ cmask, const float* __restrict__ cmaxg,
    const float* __restrict__ csumg, float* __restrict__ Up) {
  const int b = blockIdx.y;
  const int ks = blockIdx.x >> 2;
  const int mt = ((blockIdx.x >> 1) & 1) * 128;  // q offset
  const int nt = (blockIdx.x & 1) * 128;         // d offset
  const int cbase = ks * (LC / KSPLIT);
  const int tid = threadIdx.x, lane = tid & 63, wv = tid >> 6;
  const int wm = (wv >> 1) * 64, wn = (wv & 1) * 64;
  const int fr = lane & 15, kg = lane >> 4;

  const bf16* Stb = St + (size_t)b * LQ * LC;
  const float* Cb = C + (size_t)b * D_ * LC;
  const float* cmb = cmask + (size_t)b * LC;

  int qrow[4];
  float cmx[4], csv[4];
#pragma unroll
  for (int mi = 0; mi < 4; mi++) {
    qrow[mi] = mt + wm + mi * 16 + fr;
    cmx[mi] = cmaxg[b * LQ + qrow[mi]];
    csv[mi] = 1.0f / csumg[b * LQ + qrow[mi]];
  }

  f32x4 acc[4][4];
#pragma unroll
  for (int i = 0; i < 4; i++)
#pragma unroll
    for (int j = 0; j < 4; j++) acc[i][j] = {0.f, 0.f, 0.f, 0.f};

#pragma unroll 2
  for (int k0 = 0; k0 < LC / KSPLIT; k0 += 32) {
    const int c8 = cbase + k0 + kg * 8;
    const f32x4 cm0 = *(const f32x4*)(cmb + c8);
    const f32x4 cm1 = *(const f32x4*)(cmb + c8 + 4);
    bf16x8 af[4];
#pragma unroll
    for (int mi = 0; mi < 4; mi++) {
      const bf16x8 s = *(const bf16x8*)(Stb + (size_t)qrow[mi] * LC + c8);
#pragma unroll
      for (int e = 0; e < 8; ++e) {
        const float cmv = e < 4 ? cm0[e] : cm1[e - 4];
        const float lg = (float)s[e] * cmv + (1.f - cmv) * NEG_INF;
        af[mi][e] = (bf16)(__expf(lg - cmx[mi]) * csv[mi]);
      }
    }
    bf16x8 bfr[4];
#pragma unroll
    for (int ni = 0; ni < 4; ni++) {
      const float* cp = Cb + (size_t)(nt + wn + ni * 16 + fr) * LC + c8;
      const f32x4 v0 = *(const f32x4*)cp;
      const f32x4 v1 = *(const f32x4*)(cp + 4);
      bf16x8 t;
#pragma unroll
      for (int e = 0; e < 4; ++e) { t[e] = (bf16)v0[e]; t[e + 4] = (bf16)v1[e]; }
      bfr[ni] = t;
    }
#pragma unroll
    for (int mi = 0; mi < 4; mi++)
#pragma unroll
      for (int ni = 0; ni < 4; ni++)
        acc[mi][ni] = mfma16(af[mi], bfr[ni], acc[mi][ni]);
  }

  float* Ub = Up + ((size_t)(ks * B_ + b)) * D_ * LQ;
#pragma unroll
  for (int mi = 0; mi < 4; mi++)
#pragma unroll
    for (int ni = 0; ni < 4; ni++) {
      const int q = mt + wm + mi * 16 + kg * 4;
      const int d = nt + wn + ni * 16 + fr;
      *(f32x4*)(Ub + (size_t)d * LQ + q) = acc[mi][ni];
    }
}

// ---------------------------------------------------------------------------
// K3r: Utb[b][d][q] = bf16( sum_ks Up[ks][b][d][q] )
// ---------------------------------------------------------------------------
__global__ __launch_bounds__(256) void k3r_reduce(const float* __restrict__ Up,
                                                  bf16* __restrict__ Utb) {
  const size_t NP = (size_t)B_ * D_ * LQ;
  const size_t i4 = ((size_t)blockIdx.x * 256 + threadIdx.x) * 4;
  f32x4 s = *(const f32x4*)(Up + i4);
#pragma unroll
  for (int p = 1; p < KSPLIT; ++p) {
    const f32x4 v = *(const f32x4*)(Up + p * NP + i4);
    s[0] += v[0]; s[1] += v[1]; s[2] += v[2]; s[3] += v[3];
  }
  bf16x4 o = {(bf16)s[0], (bf16)s[1], (bf16)s[2], (bf16)s[3]};
  *(bf16x4*)(Utb + i4) = o;
}

// ---------------------------------------------------------------------------
// K4: A = S1 @ Qt, Bv = S1 @ U — register-fragment GEMM, barrier-free K-loop.
// A-frags straight from S1 bf16; B1 from Q (f32->bf16); B2 from Utb.
// LDS only for output transpose bounce. C read once (kept in regs).
// ---------------------------------------------------------------------------
__global__ __launch_bounds__(256) void k4_final(
    const bf16* __restrict__ S1, const float* __restrict__ C,
    const float* __restrict__ Q, const bf16* __restrict__ Utb,
    float* __restrict__ out) {
  __shared__ float bounce[64][132];

  const int b = blockIdx.y;
  const int ct = blockIdx.x >> 1, c0 = ct * 64;
  const int nt = (blockIdx.x & 1) * 128;
  const int tid = threadIdx.x, lane = tid & 63, wv = tid >> 6;
  const int wm = (wv >> 1) * 32, wn = (wv & 1) * 64;
  const int fr = lane & 15, kg = lane >> 4;

  const bf16* S1b = S1 + ((size_t)b * LC + c0) * LQ;
  const float* Cb = C + (size_t)b * D_ * LC;
  const float* Qb = Q + (size_t)b * D_ * LQ;
  const bf16* Ub = Utb + (size_t)b * D_ * LQ;

  f32x4 acc1[2][4], acc2[2][4];
#pragma unroll
  for (int i = 0; i < 2; i++)
#pragma unroll
    for (int j = 0; j < 4; j++) {
      acc1[i][j] = {0.f, 0.f, 0.f, 0.f};
      acc2[i][j] = {0.f, 0.f, 0.f, 0.f};
    }

#pragma unroll 2
  for (int k0 = 0; k0 < LQ; k0 += 32) {
    const int q8 = k0 + kg * 8;
    bf16x8 af[2];
#pragma unroll
    for (int mi = 0; mi < 2; mi++)
      af[mi] = *(const bf16x8*)(S1b + (size_t)(wm + mi * 16 + fr) * LQ + q8);
#pragma unroll
    for (int ni = 0; ni < 4; ni++) {
      const int d = nt + wn + ni * 16 + fr;
      const float* qp = Qb + (size_t)d * LQ + q8;
      const f32x4 v0 = *(const f32x4*)qp;
      const f32x4 v1 = *(const f32x4*)(qp + 4);
      bf16x8 b1;
#pragma unroll
      for (int e = 0; e < 4; ++e) { b1[e] = (bf16)v0[e]; b1[e + 4] = (bf16)v1[e]; }
      const bf16x8 b2 = *(const bf16x8*)(Ub + (size_t)d * LQ + q8);
#pragma unroll
      for (int mi = 0; mi < 2; mi++) {
        acc1[mi][ni] = mfma16(af[mi], b1, acc1[mi][ni]);
        acc2[mi][ni] = mfma16(af[mi], b2, acc2[mi][ni]);
      }
    }
  }

  // ---- epilogue: bounce acc1, write Ct/A/Ct*A (C kept in regs), then acc2 ---
  const int r4 = kg * 4, cn = fr;
#pragma unroll
  for (int mi = 0; mi < 2; mi++)
#pragma unroll
    for (int ni = 0; ni < 4; ni++)
#pragma unroll
      for (int j = 0; j < 4; j++)
        bounce[wm + mi * 16 + r4 + j][wn + ni * 16 + cn] = acc1[mi][ni][j];
  __syncthreads();

  const int ec = tid & 63, eg = tid >> 6;
  const size_t outB = (size_t)b * (4 * D_) * LC;
  float creg[32];
#pragma unroll
  for (int i = 0; i < 32; ++i) {
    const int dr = i * 4 + eg;
    const int d = nt + dr;
    const float av = bounce[ec][dr];
    const float cv = Cb[(size_t)d * LC + c0 + ec];
    creg[i] = cv;
    out[outB + (size_t)d * LC + c0 + ec] = cv;                  // Ct
    out[outB + (size_t)(D_ + d) * LC + c0 + ec] = av;           // A
    out[outB + (size_t)(2 * D_ + d) * LC + c0 + ec] = cv * av;  // Ct*A
  }
  __syncthreads();
#pragma unroll
  for (int mi = 0; mi < 2; mi++)
#pragma unroll
    for (int ni = 0; ni < 4; ni++)
#pragma unroll
      for (int j = 0; j < 4; j++)
        bounce[wm + mi * 16 + r4 + j][wn + ni * 16 + cn] = acc2[mi][ni][j];
  __syncthreads();
#pragma unroll
  for (int i = 0; i < 32; ++i) {
    const int dr = i * 4 + eg;
    const int d = nt + dr;
    const float bv = bounce[ec][dr];
    out[outB + (size_t)(3 * D_ + d) * LC + c0 + ec] = creg[i] * bv;  // Ct*Bv
  }
}

// ---------------------------------------------------------------------------
extern "C" void kernel_launch(void* const* d_in, const int* in_sizes, int n_in,
                              void* d_out, int out_size, void* d_ws, size_t ws_size,
                              hipStream_t stream) {
  (void)in_sizes; (void)n_in; (void)out_size; (void)ws_size;
  const float* C = (const float*)d_in[0];
  const float* Q = (const float*)d_in[1];
  const float* cmask = (const float*)d_in[2];
  const float* qmask = (const float*)d_in[3];
  const float* w = (const float*)d_in[4];
  float* out = (float*)d_out;

  float* ws = (float*)d_ws;
  float* Up = ws;                                   // KSPLIT*B*D*LQ fp32 (32MB)
  float* cpm = Up + (size_t)KSPLIT * B_ * D_ * LQ;  // B*32*LQ
  float* cps = cpm + B_ * 32 * LQ;                  // B*32*LQ
  float* cmaxg = cps + B_ * 32 * LQ;                // B*LQ
  float* csumg = cmaxg + B_ * LQ;                   // B*LQ
  float* bqg = csumg + B_ * LQ;                     // B*LQ
  bf16* S1b = (bf16*)(bqg + B_ * LQ);               // B*LC*LQ bf16 (32MB)
  bf16* Stb = S1b + (size_t)B_ * LC * LQ;           // B*LQ*LC bf16 (32MB)
  bf16* Utb = Stb + (size_t)B_ * LC * LQ;           // B*D_*LQ bf16 (4MB)
  bf16* Qtb = (bf16*)Up;  // overlay: Qtb dead before k3 writes Up (stream order)

  qprep<<<dim3(16, B_), 256, 0, stream>>>(Q, Qtb);
  bqkern<<<dim3(B_), 256, 0, stream>>>(Q, w, bqg);
  k1_sgemm<<<dim3(LC / 64, B_), 256, 0, stream>>>(C, Qtb, w, cmask, qmask, bqg,
                                                  S1b, Stb, cpm, cps);
  k2_colstats<<<dim3(B_), 256, 0, stream>>>(cpm, cps, cmaxg, csumg);
  k3_ugemm<<<dim3(16, B_), 256, 0, stream>>>(Stb, C, cmask, cmaxg, csumg, Up);
  k3r_reduce<<<dim3((B_ * D_ * LQ) / 1024), 256, 0, stream>>>(Up, Utb);
  k4_final<<<dim3(64, B_), 256, 0, stream>>>(S1b, C, Q, Utb, out);
}

// Round 4
// 297.083 us; speedup vs baseline: 1.7361x; 1.1559x over previous
//
#include <hip/hip_runtime.h>

// CQAttention fused pipeline for MI355X (gfx950).
// B=32, D=256, Lc=2048, Lq=256, fp32 in/out, bf16 MFMA internally.
// R4: k4 rewritten for deep in-wave MLP (A fully preloaded, 16-deep B-load
// bursts, bf16 Q precast fused into qprep, f32x4 epilogue stores).
// Workspace ~106 MB.

#define B_ 32
#define D_ 256
#define LC 2048
#define LQ 256
#define KSPLIT 4
#define NEG_INF (-1e30f)

using bf16   = __bf16;
using bf16x4 = __attribute__((ext_vector_type(4))) __bf16;
using bf16x8 = __attribute__((ext_vector_type(8))) __bf16;
using f32x4  = __attribute__((ext_vector_type(4))) float;

static __device__ __forceinline__ f32x4 mfma16(bf16x8 a, bf16x8 b, f32x4 c) {
  return __builtin_amdgcn_mfma_f32_16x16x32_bf16(a, b, c, 0, 0, 0);
}

// ---------------------------------------------------------------------------
// K0a: transpose Q (b,d,q) f32 -> Qtb (b,q,d) bf16, and elementwise cast
// Qb16[b][d][q] = bf16(Q) (fused: same data already streaming through).
// ---------------------------------------------------------------------------
__global__ __launch_bounds__(256) void qprep(const float* __restrict__ Q,
                                             bf16* __restrict__ Qtb,
                                             bf16* __restrict__ Qb16) {
  __shared__ float t[64][65];
  const int b  = blockIdx.y;
  const int qt = (blockIdx.x >> 2) * 64;
  const int dt = (blockIdx.x & 3) * 64;
  const int c  = threadIdx.x & 63, r0 = threadIdx.x >> 6;
  const float* Qb = Q + (size_t)b * D_ * LQ;
  bf16* Qcb = Qb16 + (size_t)b * D_ * LQ;
#pragma unroll
  for (int r = r0; r < 64; r += 4) {
    const float v = Qb[(size_t)(dt + r) * LQ + qt + c];
    t[r][c] = v;
    Qcb[(size_t)(dt + r) * LQ + qt + c] = (bf16)v;
  }
  __syncthreads();
  bf16* O = Qtb + (size_t)b * LQ * D_;
#pragma unroll
  for (int r = r0; r < 64; r += 4)
    O[(size_t)(qt + r) * D_ + dt + c] = (bf16)t[c][r];  // Qtb[q][d] = Q[d][q]
}

// ---------------------------------------------------------------------------
// K0b: bq[b][q] = sum_d Q[b,d,q] * w2[d]
// ---------------------------------------------------------------------------
__global__ __launch_bounds__(256) void bqkern(const float* __restrict__ Q,
                                              const float* __restrict__ w,
                                              float* __restrict__ bq) {
  const int b = blockIdx.x, q = threadIdx.x;
  const float* Qb = Q + (size_t)b * D_ * LQ;
  float acc = 0.f;
  for (int d = 0; d < D_; ++d) acc += Qb[(size_t)d * LQ + q] * w[D_ + d];
  bq[b * LQ + q] = acc;
}

// ---------------------------------------------------------------------------
// K1: S = (C*w3)^T @ Q + a[c] + bq[q], rounded to bf16.
// Emits: S1[c][q] bf16 (row-softmaxed with qmask), St[q][c] bf16 (raw,
// transposed via LDS bounce), and per-tile column partial stats.
// ---------------------------------------------------------------------------
__global__ __launch_bounds__(256) void k1_sgemm(
    const float* __restrict__ C, const bf16* __restrict__ Qtb,
    const float* __restrict__ w, const float* __restrict__ cmask,
    const float* __restrict__ qmask, const float* __restrict__ bq,
    bf16* __restrict__ S1, bf16* __restrict__ St,
    float* __restrict__ cpmax, float* __restrict__ cpsum) {
  __shared__ __align__(16) bf16 As[64][72];
  __shared__ __align__(16) bf16 Bs[256][72];  // reused as St bounce after loop
  __shared__ float ared[4][64];               // [0]/[1] reused as rml/rsl
  __shared__ float wred[4][64];
  __shared__ float wsum[4][64];
  __shared__ float cml[64];
  __shared__ float qml[256];
  __shared__ float bql[256];

  const int b = blockIdx.y, ct = blockIdx.x, c0 = ct * 64;
  const int tid = threadIdx.x, lane = tid & 63, wv = tid >> 6;
  const float* Cb = C + (size_t)b * D_ * LC;
  const bf16* Qt = Qtb + (size_t)b * LQ * D_;
  const float* w1 = w;
  const float* w3 = w + 2 * D_;

  if (tid < 64) cml[tid] = cmask[b * LC + c0 + tid];
  qml[tid] = qmask[b * LQ + tid];
  bql[tid] = bq[b * LQ + tid];

  f32x4 acc[4][4];
#pragma unroll
  for (int i = 0; i < 4; i++)
#pragma unroll
    for (int j = 0; j < 4; j++) acc[i][j] = {0.f, 0.f, 0.f, 0.f};
  float acc_a = 0.f;

  const int sm = tid & 63;   // staging: m (c)
  const int skg = tid >> 6;  // staging: k-group

  for (int k0 = 0; k0 < D_; k0 += 64) {
#pragma unroll
    for (int i = 0; i < 16; ++i) {
      const int k = skg * 16 + i, kg = k0 + k;
      const float v = Cb[(size_t)kg * LC + c0 + sm];
      As[sm][k] = (bf16)(v * w3[kg]);
      acc_a += v * w1[kg];
    }
#pragma unroll
    for (int p = 0; p < 8; ++p) {
      const int idx = (p * 256 + tid) * 8;
      const int q = idx >> 6, kk = idx & 63;
      *(bf16x8*)(&Bs[q][kk]) = *(const bf16x8*)(Qt + (size_t)q * D_ + k0 + kk);
    }
    __syncthreads();
#pragma unroll
    for (int kk = 0; kk < 64; kk += 32) {
      bf16x8 af[4], bfr[4];
#pragma unroll
      for (int mi = 0; mi < 4; mi++)
        af[mi] = *(const bf16x8*)(&As[mi * 16 + (lane & 15)][kk + (lane >> 4) * 8]);
#pragma unroll
      for (int ni = 0; ni < 4; ni++)
        bfr[ni] = *(const bf16x8*)(&Bs[wv * 64 + ni * 16 + (lane & 15)][kk + (lane >> 4) * 8]);
#pragma unroll
      for (int mi = 0; mi < 4; mi++)
#pragma unroll
        for (int ni = 0; ni < 4; ni++)
          acc[mi][ni] = mfma16(af[mi], bfr[ni], acc[mi][ni]);
    }
    __syncthreads();
  }

  ared[skg][sm] = acc_a;
  __syncthreads();

  const int r4 = (lane >> 4) * 4;  // fragment row base
  const int cn = lane & 15;        // fragment col

  // acc <- raw S rounded to bf16 (kept as floats of rounded values)
#pragma unroll
  for (int mi = 0; mi < 4; mi++)
#pragma unroll
    for (int j = 0; j < 4; j++) {
      const int m = mi * 16 + r4 + j;
      const float aval = ared[0][m] + ared[1][m] + ared[2][m] + ared[3][m];
#pragma unroll
      for (int ni = 0; ni < 4; ni++) {
        const int n = wv * 64 + ni * 16 + cn;
        const bf16 sb = (bf16)(acc[mi][ni][j] + aval + bql[n]);
        acc[mi][ni][j] = (float)sb;
      }
    }
  __syncthreads();  // ared reads done; will reuse ared[0]/[1] below

  // ---- row stats (softmax over q, qmask logits) ----
#pragma unroll
  for (int mi = 0; mi < 4; mi++)
#pragma unroll
    for (int j = 0; j < 4; j++) {
      float mx = -3.0e38f;
#pragma unroll
      for (int ni = 0; ni < 4; ni++) {
        const int n = wv * 64 + ni * 16 + cn;
        const float qm = qml[n];
        const float lg = acc[mi][ni][j] * qm + (1.f - qm) * NEG_INF;
        mx = fmaxf(mx, lg);
      }
      for (int s = 1; s < 16; s <<= 1) mx = fmaxf(mx, __shfl_xor(mx, s));
      if (cn == 0) wred[wv][mi * 16 + r4 + j] = mx;
    }
  __syncthreads();
#pragma unroll
  for (int mi = 0; mi < 4; mi++)
#pragma unroll
    for (int j = 0; j < 4; j++) {
      const int m = mi * 16 + r4 + j;
      const float gm = fmaxf(fmaxf(wred[0][m], wred[1][m]), fmaxf(wred[2][m], wred[3][m]));
      float ps = 0.f;
#pragma unroll
      for (int ni = 0; ni < 4; ni++) {
        const int n = wv * 64 + ni * 16 + cn;
        const float qm = qml[n];
        const float lg = acc[mi][ni][j] * qm + (1.f - qm) * NEG_INF;
        ps += __expf(lg - gm);
      }
      for (int s = 1; s < 16; s <<= 1) ps += __shfl_xor(ps, s);
      if (cn == 0) wsum[wv][m] = ps;
    }
  __syncthreads();
  if (tid < 64) {
    const int m = tid;
    const float rm = fmaxf(fmaxf(wred[0][m], wred[1][m]), fmaxf(wred[2][m], wred[3][m]));
    const float rs = wsum[0][m] + wsum[1][m] + wsum[2][m] + wsum[3][m];
    ared[0][m] = rm;          // rml
    ared[1][m] = 1.0f / rs;   // rsl
  }
  __syncthreads();

  // ---- write S1 = exp(masked - rm) * rsl, bf16, [c][q] ----
  bf16* S1b = S1 + ((size_t)b * LC + c0) * LQ;
#pragma unroll
  for (int mi = 0; mi < 4; mi++)
#pragma unroll
    for (int j = 0; j < 4; j++) {
      const int m = mi * 16 + r4 + j;
      const float rm = ared[0][m], rs = ared[1][m];
#pragma unroll
      for (int ni = 0; ni < 4; ni++) {
        const int n = wv * 64 + ni * 16 + cn;
        const float qm = qml[n];
        const float lg = acc[mi][ni][j] * qm + (1.f - qm) * NEG_INF;
        S1b[(size_t)m * LQ + n] = (bf16)(__expf(lg - rm) * rs);
      }
    }

  // ---- column partial stats over this 64-row tile (cmask logits) ----
#pragma unroll
  for (int ni = 0; ni < 4; ni++) {
    const int n = wv * 64 + ni * 16 + cn;
    float mx = -3.0e38f;
#pragma unroll
    for (int mi = 0; mi < 4; mi++)
#pragma unroll
      for (int j = 0; j < 4; j++) {
        const int m = mi * 16 + r4 + j;
        const float cmv = cml[m];
        const float lg = acc[mi][ni][j] * cmv + (1.f - cmv) * NEG_INF;
        mx = fmaxf(mx, lg);
      }
    mx = fmaxf(mx, __shfl_xor(mx, 16));
    mx = fmaxf(mx, __shfl_xor(mx, 32));
    float ps = 0.f;
#pragma unroll
    for (int mi = 0; mi < 4; mi++)
#pragma unroll
      for (int j = 0; j < 4; j++) {
        const int m = mi * 16 + r4 + j;
        const float cmv = cml[m];
        const float lg = acc[mi][ni][j] * cmv + (1.f - cmv) * NEG_INF;
        ps += __expf(lg - mx);
      }
    ps += __shfl_xor(ps, 16);
    ps += __shfl_xor(ps, 32);
    if ((lane >> 4) == 0) {
      cpmax[((size_t)(b * 32 + ct)) * LQ + n] = mx;
      cpsum[((size_t)(b * 32 + ct)) * LQ + n] = ps;
    }
  }

  // ---- bounce raw S through Bs -> write St[q][c0..c0+64) coalesced ----
  __syncthreads();
#pragma unroll
  for (int mi = 0; mi < 4; mi++)
#pragma unroll
    for (int ni = 0; ni < 4; ni++)
#pragma unroll
      for (int j = 0; j < 4; j++) {
        const int m = mi * 16 + r4 + j;
        const int n = wv * 64 + ni * 16 + cn;
        Bs[n][m] = (bf16)acc[mi][ni][j];
      }
  __syncthreads();
  bf16* dst = St + ((size_t)b * LQ + tid) * LC + c0;
#pragma unroll
  for (int jj = 0; jj < 8; ++jj)
    *(bf16x8*)(dst + jj * 8) = *(const bf16x8*)(&Bs[tid][jj * 8]);
}

// ---------------------------------------------------------------------------
// K2: combine 32 column-partial stats -> cmax/csum per (b,q). Exact merge.
// ---------------------------------------------------------------------------
__global__ __launch_bounds__(256) void k2_colstats(const float* __restrict__ cpmax,
                                                   const float* __restrict__ cpsum,
                                                   float* __restrict__ cmaxg,
                                                   float* __restrict__ csumg) {
  const int b = blockIdx.x, q = threadIdx.x;
  float m = -3.0e38f;
  for (int t = 0; t < 32; t++) m = fmaxf(m, cpmax[(size_t)(b * 32 + t) * LQ + q]);
  float s = 0.f;
  for (int t = 0; t < 32; t++)
    s += cpsum[(size_t)(b * 32 + t) * LQ + q] * __expf(cpmax[(size_t)(b * 32 + t) * LQ + q] - m);
  cmaxg[b * LQ + q] = m;
  csumg[b * LQ + q] = s;
}

// ---------------------------------------------------------------------------
// K3: U[q,d] = sum_c S2[c,q]*Ct[c,d] — split-K over Lc, register-fragment
// GEMM (no LDS, no barriers). A from St[q][c] + on-the-fly S2 transform;
// B from C[d][c] (f32->bf16). Writes fp32 partials Up[ks][b][d][q].
// ---------------------------------------------------------------------------
__global__ __launch_bounds__(256) void k3_ugemm(
    const bf16* __restrict__ St, const float* __restrict__ C,
    const float* __restrict__ cmask, const float* __restrict__ cmaxg,
    const float* __restrict__ csumg, float* __restrict__ Up) {
  const int b = blockIdx.y;
  const int ks = blockIdx.x >> 2;
  const int mt = ((blockIdx.x >> 1) & 1) * 128;  // q offset
  const int nt = (blockIdx.x & 1) * 128;         // d offset
  const int cbase = ks * (LC / KSPLIT);
  const int tid = threadIdx.x, lane = tid & 63, wv = tid >> 6;
  const int wm = (wv >> 1) * 64, wn = (wv & 1) * 64;
  const int fr = lane & 15, kg = lane >> 4;

  const bf16* Stb = St + (size_t)b * LQ * LC;
  const float* Cb = C + (size_t)b * D_ * LC;
  const float* cmb = cmask + (size_t)b * LC;

  int qrow[4];
  float cmx[4], csv[4];
#pragma unroll
  for (int mi = 0; mi < 4; mi++) {
    qrow[mi] = mt + wm + mi * 16 + fr;
    cmx[mi] = cmaxg[b * LQ + qrow[mi]];
    csv[mi] = 1.0f / csumg[b * LQ + qrow[mi]];
  }

  f32x4 acc[4][4];
#pragma unroll
  for (int i = 0; i < 4; i++)
#pragma unroll
    for (int j = 0; j < 4; j++) acc[i][j] = {0.f, 0.f, 0.f, 0.f};

#pragma unroll 2
  for (int k0 = 0; k0 < LC / KSPLIT; k0 += 32) {
    const int c8 = cbase + k0 + kg * 8;
    const f32x4 cm0 = *(const f32x4*)(cmb + c8);
    const f32x4 cm1 = *(const f32x4*)(cmb + c8 + 4);
    bf16x8 af[4];
#pragma unroll
    for (int mi = 0; mi < 4; mi++) {
      const bf16x8 s = *(const bf16x8*)(Stb + (size_t)qrow[mi] * LC + c8);
#pragma unroll
      for (int e = 0; e < 8; ++e) {
        const float cmv = e < 4 ? cm0[e] : cm1[e - 4];
        const float lg = (float)s[e] * cmv + (1.f - cmv) * NEG_INF;
        af[mi][e] = (bf16)(__expf(lg - cmx[mi]) * csv[mi]);
      }
    }
    bf16x8 bfr[4];
#pragma unroll
    for (int ni = 0; ni < 4; ni++) {
      const float* cp = Cb + (size_t)(nt + wn + ni * 16 + fr) * LC + c8;
      const f32x4 v0 = *(const f32x4*)cp;
      const f32x4 v1 = *(const f32x4*)(cp + 4);
      bf16x8 t;
#pragma unroll
      for (int e = 0; e < 4; ++e) { t[e] = (bf16)v0[e]; t[e + 4] = (bf16)v1[e]; }
      bfr[ni] = t;
    }
#pragma unroll
    for (int mi = 0; mi < 4; mi++)
#pragma unroll
      for (int ni = 0; ni < 4; ni++)
        acc[mi][ni] = mfma16(af[mi], bfr[ni], acc[mi][ni]);
  }

  float* Ub = Up + ((size_t)(ks * B_ + b)) * D_ * LQ;
#pragma unroll
  for (int mi = 0; mi < 4; mi++)
#pragma unroll
    for (int ni = 0; ni < 4; ni++) {
      const int q = mt + wm + mi * 16 + kg * 4;
      const int d = nt + wn + ni * 16 + fr;
      *(f32x4*)(Ub + (size_t)d * LQ + q) = acc[mi][ni];
    }
}

// ---------------------------------------------------------------------------
// K3r: Utb[b][d][q] = bf16( sum_ks Up[ks][b][d][q] )
// ---------------------------------------------------------------------------
__global__ __launch_bounds__(256) void k3r_reduce(const float* __restrict__ Up,
                                                  bf16* __restrict__ Utb) {
  const size_t NP = (size_t)B_ * D_ * LQ;
  const size_t i4 = ((size_t)blockIdx.x * 256 + threadIdx.x) * 4;
  f32x4 s = *(const f32x4*)(Up + i4);
#pragma unroll
  for (int p = 1; p < KSPLIT; ++p) {
    const f32x4 v = *(const f32x4*)(Up + p * NP + i4);
    s[0] += v[0]; s[1] += v[1]; s[2] += v[2]; s[3] += v[3];
  }
  bf16x4 o = {(bf16)s[0], (bf16)s[1], (bf16)s[2], (bf16)s[3]};
  *(bf16x4*)(Utb + i4) = o;
}

// ---------------------------------------------------------------------------
// K4: A = S1 @ Qt, Bv = S1 @ U — deep-MLP register GEMM.
// A (S1) fully preloaded (af[8][2], 16 loads in flight); per d-fragment all
// 16 B loads issued before 16 MFMAs. All-bf16 loads (Qb16 precast).
// Epilogue: LDS bounce + f32x4 stores; C read once as f32x4.
// ---------------------------------------------------------------------------
__global__ __launch_bounds__(256, 2) void k4_final(
    const bf16* __restrict__ S1, const float* __restrict__ C,
    const bf16* __restrict__ Qb16, const bf16* __restrict__ Utb,
    float* __restrict__ out) {
  __shared__ float bounce[64][131];

  const int b = blockIdx.y;
  const int ct = blockIdx.x >> 1, c0 = ct * 64;
  const int nt = (blockIdx.x & 1) * 128;
  const int tid = threadIdx.x, lane = tid & 63, wv = tid >> 6;
  const int wm = (wv >> 1) * 32, wn = (wv & 1) * 64;
  const int fr = lane & 15, kg = lane >> 4;

  const bf16* S1b = S1 + ((size_t)b * LC + c0) * LQ;
  const float* Cb = C + (size_t)b * D_ * LC;
  const bf16* Qcb = Qb16 + (size_t)b * D_ * LQ;
  const bf16* Ub = Utb + (size_t)b * D_ * LQ;

  // ---- preload all A fragments: S1 rows for this block's 64 c, full K ----
  bf16x8 af[8][2];
#pragma unroll
  for (int k = 0; k < 8; ++k)
#pragma unroll
    for (int mi = 0; mi < 2; ++mi)
      af[k][mi] = *(const bf16x8*)(S1b + (size_t)(wm + mi * 16 + fr) * LQ + k * 32 + kg * 8);

  f32x4 acc1[2][4], acc2[2][4];
#pragma unroll
  for (int i = 0; i < 2; i++)
#pragma unroll
    for (int j = 0; j < 4; j++) {
      acc1[i][j] = {0.f, 0.f, 0.f, 0.f};
      acc2[i][j] = {0.f, 0.f, 0.f, 0.f};
    }

#pragma unroll
  for (int ni = 0; ni < 4; ++ni) {
    const int d = nt + wn + ni * 16 + fr;
    const bf16* qp = Qcb + (size_t)d * LQ + kg * 8;
    const bf16* up = Ub + (size_t)d * LQ + kg * 8;
    bf16x8 b1[8], b2[8];
#pragma unroll
    for (int k = 0; k < 8; ++k) {
      b1[k] = *(const bf16x8*)(qp + k * 32);
      b2[k] = *(const bf16x8*)(up + k * 32);
    }
#pragma unroll
    for (int k = 0; k < 8; ++k) {
      acc1[0][ni] = mfma16(af[k][0], b1[k], acc1[0][ni]);
      acc1[1][ni] = mfma16(af[k][1], b1[k], acc1[1][ni]);
      acc2[0][ni] = mfma16(af[k][0], b2[k], acc2[0][ni]);
      acc2[1][ni] = mfma16(af[k][1], b2[k], acc2[1][ni]);
    }
  }

  // ---- epilogue: bounce acc1, write Ct/A/Ct*A, then acc2 -> Ct*Bv ----
  const int r4 = kg * 4;
#pragma unroll
  for (int mi = 0; mi < 2; mi++)
#pragma unroll
    for (int ni = 0; ni < 4; ni++)
#pragma unroll
      for (int j = 0; j < 4; j++)
        bounce[wm + mi * 16 + r4 + j][wn + ni * 16 + fr] = acc1[mi][ni][j];
  __syncthreads();

  const int cq = (tid & 15) * 4;    // 4 consecutive c per thread
  const int drb = tid >> 4;         // d-row base (0..15)
  const size_t outB = (size_t)b * (4 * D_) * LC;
  f32x4 creg[8];
#pragma unroll
  for (int m = 0; m < 8; ++m) {
    const int dr = drb + m * 16;
    const int d = nt + dr;
    f32x4 av;
#pragma unroll
    for (int e = 0; e < 4; ++e) av[e] = bounce[cq + e][dr];
    const f32x4 cv = *(const f32x4*)(Cb + (size_t)d * LC + c0 + cq);
    creg[m] = cv;
    f32x4 ca;
#pragma unroll
    for (int e = 0; e < 4; ++e) ca[e] = cv[e] * av[e];
    *(f32x4*)(out + outB + (size_t)d * LC + c0 + cq) = cv;                 // Ct
    *(f32x4*)(out + outB + (size_t)(D_ + d) * LC + c0 + cq) = av;          // A
    *(f32x4*)(out + outB + (size_t)(2 * D_ + d) * LC + c0 + cq) = ca;      // Ct*A
  }
  __syncthreads();
#pragma unroll
  for (int mi = 0; mi < 2; mi++)
#pragma unroll
    for (int ni = 0; ni < 4; ni++)
#pragma unroll
      for (int j = 0; j < 4; j++)
        bounce[wm + mi * 16 + r4 + j][wn + ni * 16 + fr] = acc2[mi][ni][j];
  __syncthreads();
#pragma unroll
  for (int m = 0; m < 8; ++m) {
    const int dr = drb + m * 16;
    const int d = nt + dr;
    f32x4 bv;
#pragma unroll
    for (int e = 0; e < 4; ++e) bv[e] = creg[m][e] * bounce[cq + e][dr];
    *(f32x4*)(out + outB + (size_t)(3 * D_ + d) * LC + c0 + cq) = bv;      // Ct*Bv
  }
}

// ---------------------------------------------------------------------------
extern "C" void kernel_launch(void* const* d_in, const int* in_sizes, int n_in,
                              void* d_out, int out_size, void* d_ws, size_t ws_size,
                              hipStream_t stream) {
  (void)in_sizes; (void)n_in; (void)out_size; (void)ws_size;
  const float* C = (const float*)d_in[0];
  const float* Q = (const float*)d_in[1];
  const float* cmask = (const float*)d_in[2];
  const float* qmask = (const float*)d_in[3];
  const float* w = (const float*)d_in[4];
  float* out = (float*)d_out;

  float* ws = (float*)d_ws;
  float* Up = ws;                                   // KSPLIT*B*D*LQ fp32 (32MB)
  float* cpm = Up + (size_t)KSPLIT * B_ * D_ * LQ;  // B*32*LQ
  float* cps = cpm + B_ * 32 * LQ;                  // B*32*LQ
  float* cmaxg = cps + B_ * 32 * LQ;                // B*LQ
  float* csumg = cmaxg + B_ * LQ;                   // B*LQ
  float* bqg = csumg + B_ * LQ;                     // B*LQ
  bf16* S1b = (bf16*)(bqg + B_ * LQ);               // B*LC*LQ bf16 (32MB)
  bf16* Stb = S1b + (size_t)B_ * LC * LQ;           // B*LQ*LC bf16 (32MB)
  bf16* Utb = Stb + (size_t)B_ * LC * LQ;           // B*D_*LQ bf16 (4MB)
  bf16* Qb16 = Utb + (size_t)B_ * D_ * LQ;          // B*D_*LQ bf16 (4MB)
  bf16* Qtb = (bf16*)Up;  // overlay: Qtb dead before k3 writes Up (stream order)

  qprep<<<dim3(16, B_), 256, 0, stream>>>(Q, Qtb, Qb16);
  bqkern<<<dim3(B_), 256, 0, stream>>>(Q, w, bqg);
  k1_sgemm<<<dim3(LC / 64, B_), 256, 0, stream>>>(C, Qtb, w, cmask, qmask, bqg,
                                                  S1b, Stb, cpm, cps);
  k2_colstats<<<dim3(B_), 256, 0, stream>>>(cpm, cps, cmaxg, csumg);
  k3_ugemm<<<dim3(16, B_), 256, 0, stream>>>(Stb, C, cmask, cmaxg, csumg, Up);
  k3r_reduce<<<dim3((B_ * D_ * LQ) / 1024), 256, 0, stream>>>(Up, Utb);
  k4_final<<<dim3(64, B_), 256, 0, stream>>>(S1b, C, Qb16, Utb, out);
}

// Round 5
// 295.442 us; speedup vs baseline: 1.7458x; 1.0056x over previous
//
#include <hip/hip_runtime.h>

// CQAttention fused pipeline for MI355X (gfx950).
// B=32, D=256, Lc=2048, Lq=256, fp32 in/out, bf16 MFMA internally.
// R5: S2 transform hoisted out of k3 into streaming k2s (in-place on St);
// k3 is a pure deep-MLP register GEMM (BK=64); bqkern folded into qprep;
// XCD-pairing block swizzle on k3/k4. Workspace ~105 MB.

#define B_ 32
#define D_ 256
#define LC 2048
#define LQ 256
#define KSPLIT 4
#define NEG_INF (-1e30f)

using bf16   = __bf16;
using bf16x4 = __attribute__((ext_vector_type(4))) __bf16;
using bf16x8 = __attribute__((ext_vector_type(8))) __bf16;
using f32x4  = __attribute__((ext_vector_type(4))) float;

static __device__ __forceinline__ f32x4 mfma16(bf16x8 a, bf16x8 b, f32x4 c) {
  return __builtin_amdgcn_mfma_f32_16x16x32_bf16(a, b, c, 0, 0, 0);
}

// ---------------------------------------------------------------------------
// K0a: transpose Q (b,d,q) f32 -> Qtb (b,q,d) bf16; cast Qb16[b][d][q];
// and per-(dt,q) partial dots bqp[b][dt][q] = sum_{d in dt} Q[d][q]*w2[d].
// ---------------------------------------------------------------------------
__global__ __launch_bounds__(256) void qprep(const float* __restrict__ Q,
                                             const float* __restrict__ w,
                                             bf16* __restrict__ Qtb,
                                             bf16* __restrict__ Qb16,
                                             float* __restrict__ bqp) {
  __shared__ float t[64][65];
  __shared__ float pb[4][64];
  const int b  = blockIdx.y;
  const int qt = (blockIdx.x >> 2) * 64;
  const int dtI = blockIdx.x & 3, dt = dtI * 64;
  const int c  = threadIdx.x & 63, r0 = threadIdx.x >> 6;
  const float* Qb = Q + (size_t)b * D_ * LQ;
  bf16* Qcb = Qb16 + (size_t)b * D_ * LQ;
  float partial = 0.f;
#pragma unroll
  for (int r = r0; r < 64; r += 4) {
    const float v = Qb[(size_t)(dt + r) * LQ + qt + c];
    t[r][c] = v;
    Qcb[(size_t)(dt + r) * LQ + qt + c] = (bf16)v;
    partial += v * w[D_ + dt + r];
  }
  pb[r0][c] = partial;
  __syncthreads();
  bf16* O = Qtb + (size_t)b * LQ * D_;
#pragma unroll
  for (int r = r0; r < 64; r += 4)
    O[(size_t)(qt + r) * D_ + dt + c] = (bf16)t[c][r];  // Qtb[q][d] = Q[d][q]
  if (r0 == 0)
    bqp[((size_t)(b * 4 + dtI)) * LQ + qt + c] = pb[0][c] + pb[1][c] + pb[2][c] + pb[3][c];
}

// ---------------------------------------------------------------------------
// K1: S = (C*w3)^T @ Q + a[c] + bq[q], rounded to bf16.
// Emits: S1[c][q] bf16 (row-softmaxed with qmask), St[q][c] bf16 (raw,
// transposed via LDS bounce), and per-tile column partial stats.
// ---------------------------------------------------------------------------
__global__ __launch_bounds__(256) void k1_sgemm(
    const float* __restrict__ C, const bf16* __restrict__ Qtb,
    const float* __restrict__ w, const float* __restrict__ cmask,
    const float* __restrict__ qmask, const float* __restrict__ bqp,
    bf16* __restrict__ S1, bf16* __restrict__ St,
    float* __restrict__ cpmax, float* __restrict__ cpsum) {
  __shared__ __align__(16) bf16 As[64][72];
  __shared__ __align__(16) bf16 Bs[256][72];  // reused as St bounce after loop
  __shared__ float ared[4][64];               // [0]/[1] reused as rml/rsl
  __shared__ float wred[4][64];
  __shared__ float wsum[4][64];
  __shared__ float cml[64];
  __shared__ float qml[256];
  __shared__ float bql[256];

  const int b = blockIdx.y, ct = blockIdx.x, c0 = ct * 64;
  const int tid = threadIdx.x, lane = tid & 63, wv = tid >> 6;
  const float* Cb = C + (size_t)b * D_ * LC;
  const bf16* Qt = Qtb + (size_t)b * LQ * D_;
  const float* w1 = w;
  const float* w3 = w + 2 * D_;

  if (tid < 64) cml[tid] = cmask[b * LC + c0 + tid];
  qml[tid] = qmask[b * LQ + tid];
  bql[tid] = bqp[(size_t)(b * 4 + 0) * LQ + tid] + bqp[(size_t)(b * 4 + 1) * LQ + tid] +
             bqp[(size_t)(b * 4 + 2) * LQ + tid] + bqp[(size_t)(b * 4 + 3) * LQ + tid];

  f32x4 acc[4][4];
#pragma unroll
  for (int i = 0; i < 4; i++)
#pragma unroll
    for (int j = 0; j < 4; j++) acc[i][j] = {0.f, 0.f, 0.f, 0.f};
  float acc_a = 0.f;

  const int sm = tid & 63;   // staging: m (c)
  const int skg = tid >> 6;  // staging: k-group

  for (int k0 = 0; k0 < D_; k0 += 64) {
#pragma unroll
    for (int i = 0; i < 16; ++i) {
      const int k = skg * 16 + i, kg = k0 + k;
      const float v = Cb[(size_t)kg * LC + c0 + sm];
      As[sm][k] = (bf16)(v * w3[kg]);
      acc_a += v * w1[kg];
    }
#pragma unroll
    for (int p = 0; p < 8; ++p) {
      const int idx = (p * 256 + tid) * 8;
      const int q = idx >> 6, kk = idx & 63;
      *(bf16x8*)(&Bs[q][kk]) = *(const bf16x8*)(Qt + (size_t)q * D_ + k0 + kk);
    }
    __syncthreads();
#pragma unroll
    for (int kk = 0; kk < 64; kk += 32) {
      bf16x8 af[4], bfr[4];
#pragma unroll
      for (int mi = 0; mi < 4; mi++)
        af[mi] = *(const bf16x8*)(&As[mi * 16 + (lane & 15)][kk + (lane >> 4) * 8]);
#pragma unroll
      for (int ni = 0; ni < 4; ni++)
        bfr[ni] = *(const bf16x8*)(&Bs[wv * 64 + ni * 16 + (lane & 15)][kk + (lane >> 4) * 8]);
#pragma unroll
      for (int mi = 0; mi < 4; mi++)
#pragma unroll
        for (int ni = 0; ni < 4; ni++)
          acc[mi][ni] = mfma16(af[mi], bfr[ni], acc[mi][ni]);
    }
    __syncthreads();
  }

  ared[skg][sm] = acc_a;
  __syncthreads();

  const int r4 = (lane >> 4) * 4;  // fragment row base
  const int cn = lane & 15;        // fragment col

  // acc <- raw S rounded to bf16 (kept as floats of rounded values)
#pragma unroll
  for (int mi = 0; mi < 4; mi++)
#pragma unroll
    for (int j = 0; j < 4; j++) {
      const int m = mi * 16 + r4 + j;
      const float aval = ared[0][m] + ared[1][m] + ared[2][m] + ared[3][m];
#pragma unroll
      for (int ni = 0; ni < 4; ni++) {
        const int n = wv * 64 + ni * 16 + cn;
        const bf16 sb = (bf16)(acc[mi][ni][j] + aval + bql[n]);
        acc[mi][ni][j] = (float)sb;
      }
    }
  __syncthreads();  // ared reads done; will reuse ared[0]/[1] below

  // ---- row stats (softmax over q, qmask logits) ----
#pragma unroll
  for (int mi = 0; mi < 4; mi++)
#pragma unroll
    for (int j = 0; j < 4; j++) {
      float mx = -3.0e38f;
#pragma unroll
      for (int ni = 0; ni < 4; ni++) {
        const int n = wv * 64 + ni * 16 + cn;
        const float qm = qml[n];
        const float lg = acc[mi][ni][j] * qm + (1.f - qm) * NEG_INF;
        mx = fmaxf(mx, lg);
      }
      for (int s = 1; s < 16; s <<= 1) mx = fmaxf(mx, __shfl_xor(mx, s));
      if (cn == 0) wred[wv][mi * 16 + r4 + j] = mx;
    }
  __syncthreads();
#pragma unroll
  for (int mi = 0; mi < 4; mi++)
#pragma unroll
    for (int j = 0; j < 4; j++) {
      const int m = mi * 16 + r4 + j;
      const float gm = fmaxf(fmaxf(wred[0][m], wred[1][m]), fmaxf(wred[2][m], wred[3][m]));
      float ps = 0.f;
#pragma unroll
      for (int ni = 0; ni < 4; ni++) {
        const int n = wv * 64 + ni * 16 + cn;
        const float qm = qml[n];
        const float lg = acc[mi][ni][j] * qm + (1.f - qm) * NEG_INF;
        ps += __expf(lg - gm);
      }
      for (int s = 1; s < 16; s <<= 1) ps += __shfl_xor(ps, s);
      if (cn == 0) wsum[wv][m] = ps;
    }
  __syncthreads();
  if (tid < 64) {
    const int m = tid;
    const float rm = fmaxf(fmaxf(wred[0][m], wred[1][m]), fmaxf(wred[2][m], wred[3][m]));
    const float rs = wsum[0][m] + wsum[1][m] + wsum[2][m] + wsum[3][m];
    ared[0][m] = rm;          // rml
    ared[1][m] = 1.0f / rs;   // rsl
  }
  __syncthreads();

  // ---- write S1 = exp(masked - rm) * rsl, bf16, [c][q] ----
  bf16* S1b = S1 + ((size_t)b * LC + c0) * LQ;
#pragma unroll
  for (int mi = 0; mi < 4; mi++)
#pragma unroll
    for (int j = 0; j < 4; j++) {
      const int m = mi * 16 + r4 + j;
      const float rm = ared[0][m], rs = ared[1][m];
#pragma unroll
      for (int ni = 0; ni < 4; ni++) {
        const int n = wv * 64 + ni * 16 + cn;
        const float qm = qml[n];
        const float lg = acc[mi][ni][j] * qm + (1.f - qm) * NEG_INF;
        S1b[(size_t)m * LQ + n] = (bf16)(__expf(lg - rm) * rs);
      }
    }

  // ---- column partial stats over this 64-row tile (cmask logits) ----
#pragma unroll
  for (int ni = 0; ni < 4; ni++) {
    const int n = wv * 64 + ni * 16 + cn;
    float mx = -3.0e38f;
#pragma unroll
    for (int mi = 0; mi < 4; mi++)
#pragma unroll
      for (int j = 0; j < 4; j++) {
        const int m = mi * 16 + r4 + j;
        const float cmv = cml[m];
        const float lg = acc[mi][ni][j] * cmv + (1.f - cmv) * NEG_INF;
        mx = fmaxf(mx, lg);
      }
    mx = fmaxf(mx, __shfl_xor(mx, 16));
    mx = fmaxf(mx, __shfl_xor(mx, 32));
    float ps = 0.f;
#pragma unroll
    for (int mi = 0; mi < 4; mi++)
#pragma unroll
      for (int j = 0; j < 4; j++) {
        const int m = mi * 16 + r4 + j;
        const float cmv = cml[m];
        const float lg = acc[mi][ni][j] * cmv + (1.f - cmv) * NEG_INF;
        ps += __expf(lg - mx);
      }
    ps += __shfl_xor(ps, 16);
    ps += __shfl_xor(ps, 32);
    if ((lane >> 4) == 0) {
      cpmax[((size_t)(b * 32 + ct)) * LQ + n] = mx;
      cpsum[((size_t)(b * 32 + ct)) * LQ + n] = ps;
    }
  }

  // ---- bounce raw S through Bs -> write St[q][c0..c0+64) coalesced ----
  __syncthreads();
#pragma unroll
  for (int mi = 0; mi < 4; mi++)
#pragma unroll
    for (int ni = 0; ni < 4; ni++)
#pragma unroll
      for (int j = 0; j < 4; j++) {
        const int m = mi * 16 + r4 + j;
        const int n = wv * 64 + ni * 16 + cn;
        Bs[n][m] = (bf16)acc[mi][ni][j];
      }
  __syncthreads();
  bf16* dst = St + ((size_t)b * LQ + tid) * LC + c0;
#pragma unroll
  for (int jj = 0; jj < 8; ++jj)
    *(bf16x8*)(dst + jj * 8) = *(const bf16x8*)(&Bs[tid][jj * 8]);
}

// ---------------------------------------------------------------------------
// K2: combine 32 column-partial stats -> cmax/csum per (b,q). Exact merge.
// ---------------------------------------------------------------------------
__global__ __launch_bounds__(256) void k2_colstats(const float* __restrict__ cpmax,
                                                   const float* __restrict__ cpsum,
                                                   float* __restrict__ cmaxg,
                                                   float* __restrict__ csumg) {
  const int b = blockIdx.x, q = threadIdx.x;
  float m = -3.0e38f;
  for (int t = 0; t < 32; t++) m = fmaxf(m, cpmax[(size_t)(b * 32 + t) * LQ + q]);
  float s = 0.f;
  for (int t = 0; t < 32; t++)
    s += cpsum[(size_t)(b * 32 + t) * LQ + q] * __expf(cpmax[(size_t)(b * 32 + t) * LQ + q] - m);
  cmaxg[b * LQ + q] = m;
  csumg[b * LQ + q] = s;
}

// ---------------------------------------------------------------------------
// K2s: in-place St[q][c] <- S2 = bf16( exp(mask(St) - cmax[q]) / csum[q] ).
// Pure streaming elementwise; removes all exp/mask VALU from k3.
// ---------------------------------------------------------------------------
__global__ __launch_bounds__(256) void k2s_s2(bf16* __restrict__ St,
                                              const float* __restrict__ cmask,
                                              const float* __restrict__ cmaxg,
                                              const float* __restrict__ csumg) {
  const int q = blockIdx.x, b = blockIdx.y;
  const int c8 = threadIdx.x * 8;
  bf16* row = St + ((size_t)b * LQ + q) * LC;
  const float* cmb = cmask + (size_t)b * LC;
  const float cmx = cmaxg[b * LQ + q];
  const float csv = 1.0f / csumg[b * LQ + q];
  const f32x4 cm0 = *(const f32x4*)(cmb + c8);
  const f32x4 cm1 = *(const f32x4*)(cmb + c8 + 4);
  bf16x8 v = *(const bf16x8*)(row + c8);
  bf16x8 o;
#pragma unroll
  for (int e = 0; e < 8; ++e) {
    const float cmv = e < 4 ? cm0[e] : cm1[e - 4];
    const float lg = (float)v[e] * cmv + (1.f - cmv) * NEG_INF;
    o[e] = (bf16)(__expf(lg - cmx) * csv);
  }
  *(bf16x8*)(row + c8) = o;
}

// ---------------------------------------------------------------------------
// K3: U[q,d] = sum_c S2[c,q]*Ct[c,d] — split-K over Lc, pure register GEMM.
// A = straight bf16x8 loads from S2t[q][c]; B from C f32 + cvt. BK=64.
// XCD pairing: d-tile pairs (sharing the S2t slab) adjacent on same XCD.
// ---------------------------------------------------------------------------
__global__ __launch_bounds__(256, 2) void k3_ugemm(
    const bf16* __restrict__ S2t, const float* __restrict__ C,
    float* __restrict__ Up) {
  const int g = blockIdx.x;            // 0..511
  const int x = g & 7, s = g >> 3;     // s: 0..63
  const int t = s >> 1, dtI = s & 1;   // pair slot, d-tile
  const int pair = t * 8 + x;          // 0..255
  const int b = pair >> 3, r = pair & 7;
  const int ks = r >> 1, qt = r & 1;
  const int mt = qt * 128, nt = dtI * 128;
  const int cbase = ks * (LC / KSPLIT);

  const int tid = threadIdx.x, lane = tid & 63, wv = tid >> 6;
  const int wm = (wv >> 1) * 64, wn = (wv & 1) * 64;
  const int fr = lane & 15, kg = lane >> 4;

  const bf16* S2b = S2t + (size_t)b * LQ * LC;
  const float* Cb = C + (size_t)b * D_ * LC;

  int qrow[4];
#pragma unroll
  for (int mi = 0; mi < 4; mi++) qrow[mi] = mt + wm + mi * 16 + fr;

  f32x4 acc[4][4];
#pragma unroll
  for (int i = 0; i < 4; i++)
#pragma unroll
    for (int j = 0; j < 4; j++) acc[i][j] = {0.f, 0.f, 0.f, 0.f};

#pragma unroll 2
  for (int k0 = 0; k0 < LC / KSPLIT; k0 += 64) {
    const int c8 = cbase + k0 + kg * 8;
    bf16x8 af[4][2];
#pragma unroll
    for (int mi = 0; mi < 4; mi++)
#pragma unroll
      for (int s2 = 0; s2 < 2; ++s2)
        af[mi][s2] = *(const bf16x8*)(S2b + (size_t)qrow[mi] * LC + c8 + s2 * 32);
    bf16x8 bfr[4][2];
#pragma unroll
    for (int ni = 0; ni < 4; ni++) {
      const float* cp = Cb + (size_t)(nt + wn + ni * 16 + fr) * LC + c8;
#pragma unroll
      for (int s2 = 0; s2 < 2; ++s2) {
        const f32x4 v0 = *(const f32x4*)(cp + s2 * 32);
        const f32x4 v1 = *(const f32x4*)(cp + s2 * 32 + 4);
        bf16x8 tt;
#pragma unroll
        for (int e = 0; e < 4; ++e) { tt[e] = (bf16)v0[e]; tt[e + 4] = (bf16)v1[e]; }
        bfr[ni][s2] = tt;
      }
    }
#pragma unroll
    for (int s2 = 0; s2 < 2; ++s2)
#pragma unroll
      for (int mi = 0; mi < 4; mi++)
#pragma unroll
        for (int ni = 0; ni < 4; ni++)
          acc[mi][ni] = mfma16(af[mi][s2], bfr[ni][s2], acc[mi][ni]);
  }

  float* Ub = Up + ((size_t)(ks * B_ + b)) * D_ * LQ;
#pragma unroll
  for (int mi = 0; mi < 4; mi++)
#pragma unroll
    for (int ni = 0; ni < 4; ni++) {
      const int q = mt + wm + mi * 16 + kg * 4;
      const int d = nt + wn + ni * 16 + fr;
      *(f32x4*)(Ub + (size_t)d * LQ + q) = acc[mi][ni];
    }
}

// ---------------------------------------------------------------------------
// K3r: Utb[b][d][q] = bf16( sum_ks Up[ks][b][d][q] )
// ---------------------------------------------------------------------------
__global__ __launch_bounds__(256) void k3r_reduce(const float* __restrict__ Up,
                                                  bf16* __restrict__ Utb) {
  const size_t NP = (size_t)B_ * D_ * LQ;
  const size_t i4 = ((size_t)blockIdx.x * 256 + threadIdx.x) * 4;
  f32x4 s = *(const f32x4*)(Up + i4);
#pragma unroll
  for (int p = 1; p < KSPLIT; ++p) {
    const f32x4 v = *(const f32x4*)(Up + p * NP + i4);
    s[0] += v[0]; s[1] += v[1]; s[2] += v[2]; s[3] += v[3];
  }
  bf16x4 o = {(bf16)s[0], (bf16)s[1], (bf16)s[2], (bf16)s[3]};
  *(bf16x4*)(Utb + i4) = o;
}

// ---------------------------------------------------------------------------
// K4: A = S1 @ Qt, Bv = S1 @ U — deep-MLP register GEMM. XCD pairing: nt
// pairs (sharing S1 rows) adjacent on same XCD.
// ---------------------------------------------------------------------------
__global__ __launch_bounds__(256, 2) void k4_final(
    const bf16* __restrict__ S1, const float* __restrict__ C,
    const bf16* __restrict__ Qb16, const bf16* __restrict__ Utb,
    float* __restrict__ out) {
  __shared__ float bounce[64][131];

  const int g = blockIdx.x;            // 0..2047
  const int x = g & 7, s = g >> 3;     // s: 0..255
  const int t = s >> 1, ntI = s & 1;
  const int pair = t * 8 + x;          // 0..1023
  const int b = pair >> 5, ct = pair & 31;
  const int c0 = ct * 64, nt = ntI * 128;

  const int tid = threadIdx.x, lane = tid & 63, wv = tid >> 6;
  const int wm = (wv >> 1) * 32, wn = (wv & 1) * 64;
  const int fr = lane & 15, kg = lane >> 4;

  const bf16* S1b = S1 + ((size_t)b * LC + c0) * LQ;
  const float* Cb = C + (size_t)b * D_ * LC;
  const bf16* Qcb = Qb16 + (size_t)b * D_ * LQ;
  const bf16* Ub = Utb + (size_t)b * D_ * LQ;

  // ---- preload all A fragments: S1 rows for this block's 64 c, full K ----
  bf16x8 af[8][2];
#pragma unroll
  for (int k = 0; k < 8; ++k)
#pragma unroll
    for (int mi = 0; mi < 2; ++mi)
      af[k][mi] = *(const bf16x8*)(S1b + (size_t)(wm + mi * 16 + fr) * LQ + k * 32 + kg * 8);

  f32x4 acc1[2][4], acc2[2][4];
#pragma unroll
  for (int i = 0; i < 2; i++)
#pragma unroll
    for (int j = 0; j < 4; j++) {
      acc1[i][j] = {0.f, 0.f, 0.f, 0.f};
      acc2[i][j] = {0.f, 0.f, 0.f, 0.f};
    }

#pragma unroll
  for (int ni = 0; ni < 4; ++ni) {
    const int d = nt + wn + ni * 16 + fr;
    const bf16* qp = Qcb + (size_t)d * LQ + kg * 8;
    const bf16* up = Ub + (size_t)d * LQ + kg * 8;
    bf16x8 b1[8], b2[8];
#pragma unroll
    for (int k = 0; k < 8; ++k) {
      b1[k] = *(const bf16x8*)(qp + k * 32);
      b2[k] = *(const bf16x8*)(up + k * 32);
    }
#pragma unroll
    for (int k = 0; k < 8; ++k) {
      acc1[0][ni] = mfma16(af[k][0], b1[k], acc1[0][ni]);
      acc1[1][ni] = mfma16(af[k][1], b1[k], acc1[1][ni]);
      acc2[0][ni] = mfma16(af[k][0], b2[k], acc2[0][ni]);
      acc2[1][ni] = mfma16(af[k][1], b2[k], acc2[1][ni]);
    }
  }

  // ---- epilogue: bounce acc1, write Ct/A/Ct*A, then acc2 -> Ct*Bv ----
  const int r4 = kg * 4;
#pragma unroll
  for (int mi = 0; mi < 2; mi++)
#pragma unroll
    for (int ni = 0; ni < 4; ni++)
#pragma unroll
      for (int j = 0; j < 4; j++)
        bounce[wm + mi * 16 + r4 + j][wn + ni * 16 + fr] = acc1[mi][ni][j];
  __syncthreads();

  const int cq = (tid & 15) * 4;    // 4 consecutive c per thread
  const int drb = tid >> 4;         // d-row base (0..15)
  const size_t outB = (size_t)b * (4 * D_) * LC;
  f32x4 creg[8];
#pragma unroll
  for (int m = 0; m < 8; ++m) {
    const int dr = drb + m * 16;
    const int d = nt + dr;
    f32x4 av;
#pragma unroll
    for (int e = 0; e < 4; ++e) av[e] = bounce[cq + e][dr];
    const f32x4 cv = *(const f32x4*)(Cb + (size_t)d * LC + c0 + cq);
    creg[m] = cv;
    f32x4 ca;
#pragma unroll
    for (int e = 0; e < 4; ++e) ca[e] = cv[e] * av[e];
    *(f32x4*)(out + outB + (size_t)d * LC + c0 + cq) = cv;                 // Ct
    *(f32x4*)(out + outB + (size_t)(D_ + d) * LC + c0 + cq) = av;          // A
    *(f32x4*)(out + outB + (size_t)(2 * D_ + d) * LC + c0 + cq) = ca;      // Ct*A
  }
  __syncthreads();
#pragma unroll
  for (int mi = 0; mi < 2; mi++)
#pragma unroll
    for (int ni = 0; ni < 4; ni++)
#pragma unroll
      for (int j = 0; j < 4; j++)
        bounce[wm + mi * 16 + r4 + j][wn + ni * 16 + fr] = acc2[mi][ni][j];
  __syncthreads();
#pragma unroll
  for (int m = 0; m < 8; ++m) {
    const int dr = drb + m * 16;
    const int d = nt + dr;
    f32x4 bv;
#pragma unroll
    for (int e = 0; e < 4; ++e) bv[e] = creg[m][e] * bounce[cq + e][dr];
    *(f32x4*)(out + outB + (size_t)(3 * D_ + d) * LC + c0 + cq) = bv;      // Ct*Bv
  }
}

// ---------------------------------------------------------------------------
extern "C" void kernel_launch(void* const* d_in, const int* in_sizes, int n_in,
                              void* d_out, int out_size, void* d_ws, size_t ws_size,
                              hipStream_t stream) {
  (void)in_sizes; (void)n_in; (void)out_size; (void)ws_size;
  const float* C = (const float*)d_in[0];
  const float* Q = (const float*)d_in[1];
  const float* cmask = (const float*)d_in[2];
  const float* qmask = (const float*)d_in[3];
  const float* w = (const float*)d_in[4];
  float* out = (float*)d_out;

  float* ws = (float*)d_ws;
  float* Up = ws;                                   // KSPLIT*B*D*LQ fp32 (32MB)
  float* cpm = Up + (size_t)KSPLIT * B_ * D_ * LQ;  // B*32*LQ
  float* cps = cpm + B_ * 32 * LQ;                  // B*32*LQ
  float* cmaxg = cps + B_ * 32 * LQ;                // B*LQ
  float* csumg = cmaxg + B_ * LQ;                   // B*LQ
  float* bqp = csumg + B_ * LQ;                     // B*4*LQ
  bf16* S1b = (bf16*)(bqp + B_ * 4 * LQ);           // B*LC*LQ bf16 (32MB)
  bf16* Stb = S1b + (size_t)B_ * LC * LQ;           // B*LQ*LC bf16 (32MB), ->S2 in place
  bf16* Utb = Stb + (size_t)B_ * LC * LQ;           // B*D_*LQ bf16 (4MB)
  bf16* Qb16 = Utb + (size_t)B_ * D_ * LQ;          // B*D_*LQ bf16 (4MB)
  bf16* Qtb = (bf16*)Up;  // overlay: Qtb dead before k3 writes Up (stream order)

  qprep<<<dim3(16, B_), 256, 0, stream>>>(Q, w, Qtb, Qb16, bqp);
  k1_sgemm<<<dim3(LC / 64, B_), 256, 0, stream>>>(C, Qtb, w, cmask, qmask, bqp,
                                                  S1b, Stb, cpm, cps);
  k2_colstats<<<dim3(B_), 256, 0, stream>>>(cpm, cps, cmaxg, csumg);
  k2s_s2<<<dim3(LQ, B_), 256, 0, stream>>>(Stb, cmask, cmaxg, csumg);
  k3_ugemm<<<dim3(16 * B_), 256, 0, stream>>>(Stb, C, Up);
  k3r_reduce<<<dim3((B_ * D_ * LQ) / 1024), 256, 0, stream>>>(Up, Utb);
  k4_final<<<dim3(64 * B_), 256, 0, stream>>>(S1b, C, Qb16, Utb, out);
}

// Round 6
// 250.851 us; speedup vs baseline: 2.0561x; 1.1778x over previous
//
#include <hip/hip_runtime.h>

// CQAttention fused pipeline for MI355X (gfx950).
// B=32, D=256, Lc=2048, Lq=256, fp32 in/out, bf16 MFMA internally.
// R6: S2 path eliminated algebraically — k1 emits S1t[q][c] = cmask*exp(S)
// (bf16); k3 is a pure-load GEMM; k3r applies exp(-cmax)/csum per q.
// k3/k4 restructured for 3 waves/SIMD occupancy. Workspace ~105 MB.

#define B_ 32
#define D_ 256
#define LC 2048
#define LQ 256
#define KSPLIT 4
#define NEG_INF (-1e30f)

using bf16   = __bf16;
using bf16x4 = __attribute__((ext_vector_type(4))) __bf16;
using bf16x8 = __attribute__((ext_vector_type(8))) __bf16;
using f32x4  = __attribute__((ext_vector_type(4))) float;

static __device__ __forceinline__ f32x4 mfma16(bf16x8 a, bf16x8 b, f32x4 c) {
  return __builtin_amdgcn_mfma_f32_16x16x32_bf16(a, b, c, 0, 0, 0);
}

// ---------------------------------------------------------------------------
// K0a: transpose Q (b,d,q) f32 -> Qtb (b,q,d) bf16; cast Qb16[b][d][q];
// and per-(dt,q) partial dots bqp[b][dt][q] = sum_{d in dt} Q[d][q]*w2[d].
// ---------------------------------------------------------------------------
__global__ __launch_bounds__(256) void qprep(const float* __restrict__ Q,
                                             const float* __restrict__ w,
                                             bf16* __restrict__ Qtb,
                                             bf16* __restrict__ Qb16,
                                             float* __restrict__ bqp) {
  __shared__ float t[64][65];
  __shared__ float pb[4][64];
  const int b  = blockIdx.y;
  const int qt = (blockIdx.x >> 2) * 64;
  const int dtI = blockIdx.x & 3, dt = dtI * 64;
  const int c  = threadIdx.x & 63, r0 = threadIdx.x >> 6;
  const float* Qb = Q + (size_t)b * D_ * LQ;
  bf16* Qcb = Qb16 + (size_t)b * D_ * LQ;
  float partial = 0.f;
#pragma unroll
  for (int r = r0; r < 64; r += 4) {
    const float v = Qb[(size_t)(dt + r) * LQ + qt + c];
    t[r][c] = v;
    Qcb[(size_t)(dt + r) * LQ + qt + c] = (bf16)v;
    partial += v * w[D_ + dt + r];
  }
  pb[r0][c] = partial;
  __syncthreads();
  bf16* O = Qtb + (size_t)b * LQ * D_;
#pragma unroll
  for (int r = r0; r < 64; r += 4)
    O[(size_t)(qt + r) * D_ + dt + c] = (bf16)t[c][r];  // Qtb[q][d] = Q[d][q]
  if (r0 == 0)
    bqp[((size_t)(b * 4 + dtI)) * LQ + qt + c] = pb[0][c] + pb[1][c] + pb[2][c] + pb[3][c];
}

// ---------------------------------------------------------------------------
// K1: S = (C*w3)^T @ Q + a[c] + bq[q], rounded to bf16.
// Emits: S1[c][q] bf16 (row-softmaxed with qmask),
//        S1t[q][c] bf16 = cmask[c] * exp(masked-qm S)  (unnormalized S2 basis),
//        per-tile column partial stats (cmask logits).
// ---------------------------------------------------------------------------
__global__ __launch_bounds__(256) void k1_sgemm(
    const float* __restrict__ C, const bf16* __restrict__ Qtb,
    const float* __restrict__ w, const float* __restrict__ cmask,
    const float* __restrict__ qmask, const float* __restrict__ bqp,
    bf16* __restrict__ S1, bf16* __restrict__ S1t,
    float* __restrict__ cpmax, float* __restrict__ cpsum) {
  __shared__ __align__(16) bf16 As[64][72];
  __shared__ __align__(16) bf16 Bs[256][72];  // reused as S1t bounce
  __shared__ float ared[4][64];
  __shared__ float wred[4][64];
  __shared__ float wsum[4][64];
  __shared__ float cml[64];
  __shared__ float qml[256];
  __shared__ float bql[256];

  const int b = blockIdx.y, ct = blockIdx.x, c0 = ct * 64;
  const int tid = threadIdx.x, lane = tid & 63, wv = tid >> 6;
  const float* Cb = C + (size_t)b * D_ * LC;
  const bf16* Qt = Qtb + (size_t)b * LQ * D_;
  const float* w1 = w;
  const float* w3 = w + 2 * D_;

  if (tid < 64) cml[tid] = cmask[b * LC + c0 + tid];
  qml[tid] = qmask[b * LQ + tid];
  bql[tid] = bqp[(size_t)(b * 4 + 0) * LQ + tid] + bqp[(size_t)(b * 4 + 1) * LQ + tid] +
             bqp[(size_t)(b * 4 + 2) * LQ + tid] + bqp[(size_t)(b * 4 + 3) * LQ + tid];

  f32x4 acc[4][4];
#pragma unroll
  for (int i = 0; i < 4; i++)
#pragma unroll
    for (int j = 0; j < 4; j++) acc[i][j] = {0.f, 0.f, 0.f, 0.f};
  float acc_a = 0.f;

  const int sm = tid & 63;   // staging: m (c)
  const int skg = tid >> 6;  // staging: k-group

  for (int k0 = 0; k0 < D_; k0 += 64) {
#pragma unroll
    for (int i = 0; i < 16; ++i) {
      const int k = skg * 16 + i, kg = k0 + k;
      const float v = Cb[(size_t)kg * LC + c0 + sm];
      As[sm][k] = (bf16)(v * w3[kg]);
      acc_a += v * w1[kg];
    }
#pragma unroll
    for (int p = 0; p < 8; ++p) {
      const int idx = (p * 256 + tid) * 8;
      const int q = idx >> 6, kk = idx & 63;
      *(bf16x8*)(&Bs[q][kk]) = *(const bf16x8*)(Qt + (size_t)q * D_ + k0 + kk);
    }
    __syncthreads();
#pragma unroll
    for (int kk = 0; kk < 64; kk += 32) {
      bf16x8 af[4], bfr[4];
#pragma unroll
      for (int mi = 0; mi < 4; mi++)
        af[mi] = *(const bf16x8*)(&As[mi * 16 + (lane & 15)][kk + (lane >> 4) * 8]);
#pragma unroll
      for (int ni = 0; ni < 4; ni++)
        bfr[ni] = *(const bf16x8*)(&Bs[wv * 64 + ni * 16 + (lane & 15)][kk + (lane >> 4) * 8]);
#pragma unroll
      for (int mi = 0; mi < 4; mi++)
#pragma unroll
        for (int ni = 0; ni < 4; ni++)
          acc[mi][ni] = mfma16(af[mi], bfr[ni], acc[mi][ni]);
    }
    __syncthreads();
  }

  ared[skg][sm] = acc_a;
  __syncthreads();

  const int r4 = (lane >> 4) * 4;  // fragment row base
  const int cn = lane & 15;        // fragment col

  // acc <- raw S rounded to bf16 (kept as floats of rounded values)
#pragma unroll
  for (int mi = 0; mi < 4; mi++)
#pragma unroll
    for (int j = 0; j < 4; j++) {
      const int m = mi * 16 + r4 + j;
      const float aval = ared[0][m] + ared[1][m] + ared[2][m] + ared[3][m];
#pragma unroll
      for (int ni = 0; ni < 4; ni++) {
        const int n = wv * 64 + ni * 16 + cn;
        const bf16 sb = (bf16)(acc[mi][ni][j] + aval + bql[n]);
        acc[mi][ni][j] = (float)sb;
      }
    }

  // ---- column partial stats (cmask logits, raw acc) ----
#pragma unroll
  for (int ni = 0; ni < 4; ni++) {
    const int n = wv * 64 + ni * 16 + cn;
    float mx = -3.0e38f;
#pragma unroll
    for (int mi = 0; mi < 4; mi++)
#pragma unroll
      for (int j = 0; j < 4; j++) {
        const int m = mi * 16 + r4 + j;
        const float cmv = cml[m];
        const float lg = acc[mi][ni][j] * cmv + (1.f - cmv) * NEG_INF;
        mx = fmaxf(mx, lg);
      }
    mx = fmaxf(mx, __shfl_xor(mx, 16));
    mx = fmaxf(mx, __shfl_xor(mx, 32));
    float ps = 0.f;
#pragma unroll
    for (int mi = 0; mi < 4; mi++)
#pragma unroll
      for (int j = 0; j < 4; j++) {
        const int m = mi * 16 + r4 + j;
        const float cmv = cml[m];
        const float lg = acc[mi][ni][j] * cmv + (1.f - cmv) * NEG_INF;
        ps += __expf(lg - mx);
      }
    ps += __shfl_xor(ps, 16);
    ps += __shfl_xor(ps, 32);
    if ((lane >> 4) == 0) {
      cpmax[((size_t)(b * 32 + ct)) * LQ + n] = mx;
      cpsum[((size_t)(b * 32 + ct)) * LQ + n] = ps;
    }
  }

  // ---- row max (qmask logits) ----
#pragma unroll
  for (int mi = 0; mi < 4; mi++)
#pragma unroll
    for (int j = 0; j < 4; j++) {
      float mx = -3.0e38f;
#pragma unroll
      for (int ni = 0; ni < 4; ni++) {
        const int n = wv * 64 + ni * 16 + cn;
        const float qm = qml[n];
        const float lg = acc[mi][ni][j] * qm + (1.f - qm) * NEG_INF;
        mx = fmaxf(mx, lg);
      }
      for (int s = 1; s < 16; s <<= 1) mx = fmaxf(mx, __shfl_xor(mx, s));
      if (cn == 0) wred[wv][mi * 16 + r4 + j] = mx;
    }
  __syncthreads();

  // ---- e = exp(lg - rm) overwrites acc; row sums ----
  float rmv[4][4];
#pragma unroll
  for (int mi = 0; mi < 4; mi++)
#pragma unroll
    for (int j = 0; j < 4; j++) {
      const int m = mi * 16 + r4 + j;
      const float rm = fmaxf(fmaxf(wred[0][m], wred[1][m]), fmaxf(wred[2][m], wred[3][m]));
      rmv[mi][j] = rm;
      float ps = 0.f;
#pragma unroll
      for (int ni = 0; ni < 4; ni++) {
        const int n = wv * 64 + ni * 16 + cn;
        const float qm = qml[n];
        const float lg = acc[mi][ni][j] * qm + (1.f - qm) * NEG_INF;
        const float e = __expf(lg - rm);
        acc[mi][ni][j] = e;
        ps += e;
      }
      for (int s = 1; s < 16; s <<= 1) ps += __shfl_xor(ps, s);
      if (cn == 0) wsum[wv][m] = ps;
    }
  __syncthreads();

  // ---- write S1 = e * rsl ; bounce S1t = bf16(e * cml * exp(rm)) ----
  bf16* S1b = S1 + ((size_t)b * LC + c0) * LQ;
#pragma unroll
  for (int mi = 0; mi < 4; mi++)
#pragma unroll
    for (int j = 0; j < 4; j++) {
      const int m = mi * 16 + r4 + j;
      const float rs = wsum[0][m] + wsum[1][m] + wsum[2][m] + wsum[3][m];
      const float rsl = 1.0f / rs;
      const float f = cml[m] * __expf(rmv[mi][j]);
#pragma unroll
      for (int ni = 0; ni < 4; ni++) {
        const int n = wv * 64 + ni * 16 + cn;
        const float e = acc[mi][ni][j];
        S1b[(size_t)m * LQ + n] = (bf16)(e * rsl);
        Bs[n][m] = (bf16)(e * f);
      }
    }
  __syncthreads();
  bf16* dst = S1t + ((size_t)b * LQ + tid) * LC + c0;
#pragma unroll
  for (int jj = 0; jj < 8; ++jj)
    *(bf16x8*)(dst + jj * 8) = *(const bf16x8*)(&Bs[tid][jj * 8]);
}

// ---------------------------------------------------------------------------
// K2: combine 32 column-partial stats -> cscl[b][q] = exp(-cmax)/csum.
// ---------------------------------------------------------------------------
__global__ __launch_bounds__(256) void k2_colstats(const float* __restrict__ cpmax,
                                                   const float* __restrict__ cpsum,
                                                   float* __restrict__ cscl) {
  const int b = blockIdx.x, q = threadIdx.x;
  float m = -3.0e38f;
  for (int t = 0; t < 32; t++) m = fmaxf(m, cpmax[(size_t)(b * 32 + t) * LQ + q]);
  float s = 0.f;
  for (int t = 0; t < 32; t++)
    s += cpsum[(size_t)(b * 32 + t) * LQ + q] * __expf(cpmax[(size_t)(b * 32 + t) * LQ + q] - m);
  cscl[b * LQ + q] = __expf(-m) / s;
}

// ---------------------------------------------------------------------------
// K3: Uraw[q,d] = sum_c S1t[q,c]*Ct[c,d] — split-K, pure-load register GEMM.
// Quad-XCD swizzle: 4 blocks of one (b,ks) group (2 share the C slab, 2 the
// S1t slab) land on the same XCD L2.
// ---------------------------------------------------------------------------
__global__ __launch_bounds__(256, 3) void k3_ugemm(
    const bf16* __restrict__ S1t, const float* __restrict__ C,
    float* __restrict__ Up) {
  const int g = blockIdx.x;            // 0..511
  const int x = g & 7, s = g >> 3;     // s: 0..63
  const int quad = (s >> 2) * 8 + x;   // 0..127 : (b, ks)
  const int inner = s & 3;             // (qt, dtI)
  const int b = quad >> 2, ks = quad & 3;
  const int qt = inner >> 1, dtI = inner & 1;
  const int mt = qt * 128, nt = dtI * 128;
  const int cbase = ks * (LC / KSPLIT);

  const int tid = threadIdx.x, lane = tid & 63, wv = tid >> 6;
  const int wm = (wv >> 1) * 64, wn = (wv & 1) * 64;
  const int fr = lane & 15, kg = lane >> 4;

  const bf16* Sb = S1t + (size_t)b * LQ * LC;
  const float* Cb = C + (size_t)b * D_ * LC;

  int qrow[4];
#pragma unroll
  for (int mi = 0; mi < 4; mi++) qrow[mi] = mt + wm + mi * 16 + fr;

  f32x4 acc[4][4];
#pragma unroll
  for (int i = 0; i < 4; i++)
#pragma unroll
    for (int j = 0; j < 4; j++) acc[i][j] = {0.f, 0.f, 0.f, 0.f};

#pragma unroll 2
  for (int k0 = 0; k0 < LC / KSPLIT; k0 += 64) {
    const int c8 = cbase + k0 + kg * 8;
    bf16x8 af[4][2];
#pragma unroll
    for (int mi = 0; mi < 4; mi++)
#pragma unroll
      for (int s2 = 0; s2 < 2; ++s2)
        af[mi][s2] = *(const bf16x8*)(Sb + (size_t)qrow[mi] * LC + c8 + s2 * 32);
    bf16x8 bfr[4][2];
#pragma unroll
    for (int ni = 0; ni < 4; ni++) {
      const float* cp = Cb + (size_t)(nt + wn + ni * 16 + fr) * LC + c8;
#pragma unroll
      for (int s2 = 0; s2 < 2; ++s2) {
        const f32x4 v0 = *(const f32x4*)(cp + s2 * 32);
        const f32x4 v1 = *(const f32x4*)(cp + s2 * 32 + 4);
        bf16x8 tt;
#pragma unroll
        for (int e = 0; e < 4; ++e) { tt[e] = (bf16)v0[e]; tt[e + 4] = (bf16)v1[e]; }
        bfr[ni][s2] = tt;
      }
    }
#pragma unroll
    for (int s2 = 0; s2 < 2; ++s2)
#pragma unroll
      for (int mi = 0; mi < 4; mi++)
#pragma unroll
        for (int ni = 0; ni < 4; ni++)
          acc[mi][ni] = mfma16(af[mi][s2], bfr[ni][s2], acc[mi][ni]);
  }

  float* Ub = Up + ((size_t)(ks * B_ + b)) * D_ * LQ;
#pragma unroll
  for (int mi = 0; mi < 4; mi++)
#pragma unroll
    for (int ni = 0; ni < 4; ni++) {
      const int q = mt + wm + mi * 16 + kg * 4;
      const int d = nt + wn + ni * 16 + fr;
      *(f32x4*)(Ub + (size_t)d * LQ + q) = acc[mi][ni];
    }
}

// ---------------------------------------------------------------------------
// K3r: Utb[b][d][q] = bf16( cscl[b][q] * sum_ks Up[ks][b][d][q] )
// ---------------------------------------------------------------------------
__global__ __launch_bounds__(256) void k3r_reduce(const float* __restrict__ Up,
                                                  const float* __restrict__ cscl,
                                                  bf16* __restrict__ Utb) {
  const size_t NP = (size_t)B_ * D_ * LQ;
  const size_t i4 = ((size_t)blockIdx.x * 256 + threadIdx.x) * 4;
  const int b = (int)(i4 >> 16);       // D_*LQ = 65536
  const int q = (int)(i4 & (LQ - 1));
  f32x4 s = *(const f32x4*)(Up + i4);
#pragma unroll
  for (int p = 1; p < KSPLIT; ++p) {
    const f32x4 v = *(const f32x4*)(Up + p * NP + i4);
    s[0] += v[0]; s[1] += v[1]; s[2] += v[2]; s[3] += v[3];
  }
  const f32x4 sc = *(const f32x4*)(cscl + b * LQ + q);
  bf16x4 o = {(bf16)(s[0] * sc[0]), (bf16)(s[1] * sc[1]),
              (bf16)(s[2] * sc[2]), (bf16)(s[3] * sc[3])};
  *(bf16x4*)(Utb + i4) = o;
}

// ---------------------------------------------------------------------------
// K4: A = S1 @ Qt, Bv = S1 @ U — k-outer register GEMM, no big preloads
// (VGPR-lean for 3 waves/SIMD). XCD pairing on nt (S1 sharing).
// ---------------------------------------------------------------------------
__global__ __launch_bounds__(256, 3) void k4_final(
    const bf16* __restrict__ S1, const float* __restrict__ C,
    const bf16* __restrict__ Qb16, const bf16* __restrict__ Utb,
    float* __restrict__ out) {
  __shared__ float bounce[64][131];

  const int g = blockIdx.x;            // 0..2047
  const int x = g & 7, s = g >> 3;     // s: 0..255
  const int t = s >> 1, ntI = s & 1;
  const int pair = t * 8 + x;          // 0..1023
  const int b = pair >> 5, ct = pair & 31;
  const int c0 = ct * 64, nt = ntI * 128;

  const int tid = threadIdx.x, lane = tid & 63, wv = tid >> 6;
  const int wm = (wv >> 1) * 32, wn = (wv & 1) * 64;
  const int fr = lane & 15, kg = lane >> 4;

  const bf16* S1b = S1 + ((size_t)b * LC + c0) * LQ;
  const float* Cb = C + (size_t)b * D_ * LC;
  const bf16* Qcb = Qb16 + (size_t)b * D_ * LQ;
  const bf16* Ub = Utb + (size_t)b * D_ * LQ;

  f32x4 acc1[2][4], acc2[2][4];
#pragma unroll
  for (int i = 0; i < 2; i++)
#pragma unroll
    for (int j = 0; j < 4; j++) {
      acc1[i][j] = {0.f, 0.f, 0.f, 0.f};
      acc2[i][j] = {0.f, 0.f, 0.f, 0.f};
    }

#pragma unroll
  for (int k = 0; k < 8; ++k) {
    const int q8 = k * 32 + kg * 8;
    const bf16x8 af0 = *(const bf16x8*)(S1b + (size_t)(wm + fr) * LQ + q8);
    const bf16x8 af1 = *(const bf16x8*)(S1b + (size_t)(wm + 16 + fr) * LQ + q8);
#pragma unroll
    for (int ni = 0; ni < 4; ++ni) {
      const int d = nt + wn + ni * 16 + fr;
      const bf16x8 b1 = *(const bf16x8*)(Qcb + (size_t)d * LQ + q8);
      const bf16x8 b2 = *(const bf16x8*)(Ub + (size_t)d * LQ + q8);
      acc1[0][ni] = mfma16(af0, b1, acc1[0][ni]);
      acc1[1][ni] = mfma16(af1, b1, acc1[1][ni]);
      acc2[0][ni] = mfma16(af0, b2, acc2[0][ni]);
      acc2[1][ni] = mfma16(af1, b2, acc2[1][ni]);
    }
  }

  // ---- epilogue: bounce acc1, write Ct/A/Ct*A, then acc2 -> Ct*Bv ----
  const int r4 = kg * 4;
#pragma unroll
  for (int mi = 0; mi < 2; mi++)
#pragma unroll
    for (int ni = 0; ni < 4; ni++)
#pragma unroll
      for (int j = 0; j < 4; j++)
        bounce[wm + mi * 16 + r4 + j][wn + ni * 16 + fr] = acc1[mi][ni][j];
  __syncthreads();

  const int cq = (tid & 15) * 4;    // 4 consecutive c per thread
  const int drb = tid >> 4;         // d-row base (0..15)
  const size_t outB = (size_t)b * (4 * D_) * LC;
  f32x4 creg[8];
#pragma unroll
  for (int m = 0; m < 8; ++m) {
    const int dr = drb + m * 16;
    const int d = nt + dr;
    f32x4 av;
#pragma unroll
    for (int e = 0; e < 4; ++e) av[e] = bounce[cq + e][dr];
    const f32x4 cv = *(const f32x4*)(Cb + (size_t)d * LC + c0 + cq);
    creg[m] = cv;
    f32x4 ca;
#pragma unroll
    for (int e = 0; e < 4; ++e) ca[e] = cv[e] * av[e];
    *(f32x4*)(out + outB + (size_t)d * LC + c0 + cq) = cv;                 // Ct
    *(f32x4*)(out + outB + (size_t)(D_ + d) * LC + c0 + cq) = av;          // A
    *(f32x4*)(out + outB + (size_t)(2 * D_ + d) * LC + c0 + cq) = ca;      // Ct*A
  }
  __syncthreads();
#pragma unroll
  for (int mi = 0; mi < 2; mi++)
#pragma unroll
    for (int ni = 0; ni < 4; ni++)
#pragma unroll
      for (int j = 0; j < 4; j++)
        bounce[wm + mi * 16 + r4 + j][wn + ni * 16 + fr] = acc2[mi][ni][j];
  __syncthreads();
#pragma unroll
  for (int m = 0; m < 8; ++m) {
    const int dr = drb + m * 16;
    const int d = nt + dr;
    f32x4 bv;
#pragma unroll
    for (int e = 0; e < 4; ++e) bv[e] = creg[m][e] * bounce[cq + e][dr];
    *(f32x4*)(out + outB + (size_t)(3 * D_ + d) * LC + c0 + cq) = bv;      // Ct*Bv
  }
}

// ---------------------------------------------------------------------------
extern "C" void kernel_launch(void* const* d_in, const int* in_sizes, int n_in,
                              void* d_out, int out_size, void* d_ws, size_t ws_size,
                              hipStream_t stream) {
  (void)in_sizes; (void)n_in; (void)out_size; (void)ws_size;
  const float* C = (const float*)d_in[0];
  const float* Q = (const float*)d_in[1];
  const float* cmask = (const float*)d_in[2];
  const float* qmask = (const float*)d_in[3];
  const float* w = (const float*)d_in[4];
  float* out = (float*)d_out;

  float* ws = (float*)d_ws;
  float* Up = ws;                                   // KSPLIT*B*D*LQ fp32 (33.5MB)
  float* cpm = Up + (size_t)KSPLIT * B_ * D_ * LQ;  // B*32*LQ
  float* cps = cpm + B_ * 32 * LQ;                  // B*32*LQ
  float* cscl = cps + B_ * 32 * LQ;                 // B*LQ
  float* bqp = cscl + B_ * LQ;                      // B*4*LQ
  bf16* S1b = (bf16*)(bqp + B_ * 4 * LQ);           // B*LC*LQ bf16 (33.5MB)
  bf16* S1tb = S1b + (size_t)B_ * LC * LQ;          // B*LQ*LC bf16 (33.5MB)
  bf16* Utb = S1tb + (size_t)B_ * LC * LQ;          // B*D_*LQ bf16 (4MB)
  bf16* Qb16 = Utb + (size_t)B_ * D_ * LQ;          // B*D_*LQ bf16 (4MB)
  bf16* Qtb = (bf16*)Up;  // overlay: Qtb dead before k3 writes Up (stream order)

  qprep<<<dim3(16, B_), 256, 0, stream>>>(Q, w, Qtb, Qb16, bqp);
  k1_sgemm<<<dim3(LC / 64, B_), 256, 0, stream>>>(C, Qtb, w, cmask, qmask, bqp,
                                                  S1b, S1tb, cpm, cps);
  k2_colstats<<<dim3(B_), 256, 0, stream>>>(cpm, cps, cscl);
  k3_ugemm<<<dim3(16 * B_), 256, 0, stream>>>(S1tb, C, Up);
  k3r_reduce<<<dim3((B_ * D_ * LQ) / 1024), 256, 0, stream>>>(Up, cscl, Utb);
  k4_final<<<dim3(64 * B_), 256, 0, stream>>>(S1b, C, Qb16, Utb, out);
}